// Round 9
// baseline (1709.636 us; speedup 1.0000x reference)
//
#include <hip/hip_runtime.h>

typedef __bf16 bf16;
typedef _Float16 f16;
typedef unsigned short u16;
typedef __bf16 bf16x8 __attribute__((ext_vector_type(8)));
typedef _Float16 f16x8 __attribute__((ext_vector_type(8)));
typedef unsigned short u16x8 __attribute__((ext_vector_type(8)));
typedef float f32x4 __attribute__((ext_vector_type(4)));

#define TOK   2048   // B*S
#define SEQ   1024
#define HIDD  2048
#define NHEADS 16
#define QCD   1536
#define KVCD  512
#define ROPED 64
#define NOPED 128
#define QDIM  192    // NOPE+ROPE
#define VHD   128
#define KVD   576
#define KVDP  640
#define INTERD 1408
#define GUD   2816   // 2*INTER
#define RMS_EPS 1e-6f
#define SPS   64.0f          // split pre-scale (both operands)
#define OSC   (1.0f/4096.0f) // epilogue descale (64*64)

__device__ inline void split64(float v, f16& h, f16& l) {
    v *= SPS; h = (f16)v; l = (f16)(v - (float)h);
}

__device__ inline void gl_lds16(const void* g, void* l) {
    __builtin_amdgcn_global_load_lds(
        (const __attribute__((address_space(1))) void*)g,
        (__attribute__((address_space(3))) void*)l,
        16, 0, 0);
}

#define WAITN(N) asm volatile("s_waitcnt vmcnt(" #N ")" ::: "memory")

// ---------------------------------------------------------------------------
// Batched expert conversion (gate/up column-INTERLEAVED for fused-silu GEMM):
// z=0: gate n -> dGU row 2n; z=1: up n -> dGU row 2n+1; z=2: down -> dD.
__global__ __launch_bounds__(256) void tconv_ex3_kernel(const float* __restrict__ gate,
                                                        const float* __restrict__ up,
                                                        const float* __restrict__ down,
                                                        bf16* __restrict__ dGU,
                                                        bf16* __restrict__ dD) {
    const float* src; bf16* dst; int K, N, rowMul, rowAdd;
    if (blockIdx.z == 0)      { src = gate; dst = dGU; K = HIDD;   N = INTERD; rowMul = 2; rowAdd = 0; }
    else if (blockIdx.z == 1) { src = up;   dst = dGU; K = HIDD;   N = INTERD; rowMul = 2; rowAdd = 1; }
    else                      { src = down; dst = dD;  K = INTERD; N = HIDD;   rowMul = 1; rowAdd = 0; }
    int nb = blockIdx.x * 32, kb = blockIdx.y * 32;
    if (nb >= N || kb >= K) return;
    __shared__ float tile[32][33];
    int tx = threadIdx.x & 31, ty = threadIdx.x >> 5;
#pragma unroll
    for (int i = 0; i < 32; i += 8)
        tile[ty + i][tx] = src[(long)(kb + ty + i) * N + nb + tx];
    __syncthreads();
#pragma unroll
    for (int i = 0; i < 32; i += 8) {
        int n = nb + ty + i;
        dst[(long)(n * rowMul + rowAdd) * K + kb + tx] = (bf16)tile[tx][ty + i];
    }
}

// Transpose-convert f16 TRIPLE B-pattern [hi|lo|hi] of 64*w: src (K,N) -> dst (Npad,3K).
__global__ __launch_bounds__(256) void tconv3h_kernel(const float* __restrict__ src,
                                                      f16* __restrict__ dst,
                                                      int K, int N, int Npad) {
    __shared__ float tile[32][33];
    int nb = blockIdx.x * 32, kb = blockIdx.y * 32;
    int tx = threadIdx.x & 31, ty = threadIdx.x >> 5;
#pragma unroll
    for (int i = 0; i < 32; i += 8) {
        int k = kb + ty + i, n = nb + tx;
        tile[ty + i][tx] = (k < K && n < N) ? src[(long)k * N + n] : 0.f;
    }
    __syncthreads();
#pragma unroll
    for (int i = 0; i < 32; i += 8) {
        int n = nb + ty + i, k = kb + tx;
        if (n < Npad && k < K) {
            f16 h, l; split64(tile[tx][ty + i], h, l);
            long base = (long)n * (3 * K) + k;
            dst[base] = h; dst[base + K] = l; dst[base + 2 * K] = h;
        }
    }
}

// ---------------------------------------------------------------------------
// NT GEMM, TMxTN tile, BK=64, global_load_lds w16, XOR-swizzled LDS (rule 21),
// counted-vmcnt prefetch pipeline (T4). PF=2 shapes: SINGLE barrier per iter
// (WAITN -> barrier -> stage -> compute; WAR-safe since barrier-t implies all
// waves finished compute t-1). PF=1 (128x128): 2-barrier form.
// mode 0: f32 = val*osc; 2: f32 = val*osc + aux[row*auxLd+col];
// mode 3: f32 += (aux?aux[row*auxLd]:1)*val*osc;
// mode 5: scatter f32 out[idx[row]*ldc+col] += aux[idx[row]*auxLd]*val*osc (row<cnt);
// mode 6: f16 triple [hi@ci | hi@ci+auxLd | lo@ci+2auxLd] of val*osc;
// mode 7: fused silu-mul (interleaved g/u cols): even lanes store
//         bf16(silu(g)*u) at Cv[row*auxLd + col/2].
template<int F16, int TM, int TN>
__global__ __launch_bounds__(256) void gemm_bt_kernel(
    const u16* __restrict__ A, const u16* __restrict__ B, void* __restrict__ Cv,
    const float* __restrict__ aux, const int* __restrict__ idx,
    const int* __restrict__ cntPtr,
    int K, int lda, int ldb, int ldc,
    long sA, long sB, long sC,
    int mode, int auxLd, float osc)
{
    constexpr int AM = TM / 32;
    constexpr int AN = TN / 32;
    constexpr int NBUF = (TM + TN > 192) ? 2 : 3;
    constexpr int PF = NBUF - 1;
    constexpr int L = TM / 32 + TN / 32;            // gl_lds loads per wave per stage
    __shared__ u16 As[NBUF][TM * 64];
    __shared__ u16 Bs[NBUF][TN * 64];
    const int bn = blockIdx.x, bm = blockIdx.y, z = blockIdx.z;
    int cnt = 1 << 30;
    if (cntPtr) {
        cnt = *cntPtr;
        int pad = (cnt + TM - 1) & ~(TM - 1);
        if (bm * TM >= pad) return;
    }
    const int tid = threadIdx.x, lane = tid & 63, w = tid >> 6;
    const int wm = w >> 1, wn = w & 1;
    const int lr = lane & 15;
    const int srow = lane >> 3, c16 = lane & 7;   // staging: 8 rows x 8 granules
    const u16* Ab = A + (long)z * sA + (long)bm * TM * lda;
    const u16* Bb = B + (long)z * sB + (long)bn * TN * ldb;
    f32x4 acc[AM][AN] = {};

    auto stage = [&](int buf, int k0) {
#pragma unroll
        for (int i = 0; i < TM / 32; i++) {
            int rb = i * 32 + w * 8;               // wave-uniform LDS row base
            int row = rb + srow;
            int gc = ((c16 ^ (row & 7)) << 3);     // inverse-swizzled source col
            gl_lds16(&Ab[(long)row * lda + k0 + gc], &As[buf][rb * 64]);
        }
#pragma unroll
        for (int i = 0; i < TN / 32; i++) {
            int rb = i * 32 + w * 8;
            int row = rb + srow;
            int gc = ((c16 ^ (row & 7)) << 3);
            gl_lds16(&Bb[(long)row * ldb + k0 + gc], &Bs[buf][rb * 64]);
        }
    };
    auto compute = [&](int cur) {
#pragma unroll
        for (int ks = 0; ks < 2; ks++) {
            u16x8 af[AM], bfr[AN];
#pragma unroll
            for (int mi = 0; mi < AM; mi++) {
                int row = wm * (TM / 2) + mi * 16 + lr;
                int cg = (ks * 4 + (lane >> 4)) ^ (row & 7);
                af[mi] = *(const u16x8*)&As[cur][row * 64 + cg * 8];
            }
#pragma unroll
            for (int ni = 0; ni < AN; ni++) {
                int row = wn * (TN / 2) + ni * 16 + lr;
                int cg = (ks * 4 + (lane >> 4)) ^ (row & 7);
                bfr[ni] = *(const u16x8*)&Bs[cur][row * 64 + cg * 8];
            }
#pragma unroll
            for (int mi = 0; mi < AM; mi++)
#pragma unroll
                for (int ni = 0; ni < AN; ni++) {
                    if constexpr (F16)
                        acc[mi][ni] = __builtin_amdgcn_mfma_f32_16x16x32_f16(
                            __builtin_bit_cast(f16x8, af[mi]),
                            __builtin_bit_cast(f16x8, bfr[ni]), acc[mi][ni], 0, 0, 0);
                    else
                        acc[mi][ni] = __builtin_amdgcn_mfma_f32_16x16x32_bf16(
                            __builtin_bit_cast(bf16x8, af[mi]),
                            __builtin_bit_cast(bf16x8, bfr[ni]), acc[mi][ni], 0, 0, 0);
                }
        }
    };

    const int nk = K >> 6;
#pragma unroll
    for (int p = 0; p < PF; ++p) if (p < nk) stage(p, p << 6);

    if constexpr (PF == 2) {
        // single barrier per iteration
        for (int t = 0; t < nk; ++t) {
            if (t < nk - 1) { if constexpr (L == 4) WAITN(4); else WAITN(6); }
            else            WAITN(0);
            __builtin_amdgcn_s_barrier();
            __builtin_amdgcn_sched_barrier(0);
            if (t + PF < nk) stage((t + PF) % NBUF, (t + PF) << 6);
            compute(t % NBUF);
        }
    } else {
        for (int t = 0; t < nk; ++t) {
            if (t + 1 < nk) stage((t + 1) & 1, (t + 1) << 6);
            if (t + 1 < nk) WAITN(8);
            else            WAITN(0);
            __builtin_amdgcn_s_barrier();
            __builtin_amdgcn_sched_barrier(0);
            compute(t & 1);
            __builtin_amdgcn_s_barrier();
        }
    }

    const int r0 = (lane >> 4) << 2;
    const int rowBase = bm * TM + wm * (TM / 2);
    const int colBase = bn * TN + wn * (TN / 2);
#pragma unroll
    for (int mi = 0; mi < AM; mi++) {
#pragma unroll
        for (int ni = 0; ni < AN; ni++) {
#pragma unroll
            for (int r = 0; r < 4; r++) {
                int row = rowBase + mi * 16 + r0 + r;
                int col = colBase + ni * 16 + lr;
                float val = acc[mi][ni][r] * osc;
                long ci = (long)z * sC + (long)row * ldc + col;
                if (mode == 0) {
                    ((float*)Cv)[ci] = val;
                } else if (mode == 2) {
                    ((float*)Cv)[ci] = val + aux[(long)row * auxLd + col];
                } else if (mode == 3) {
                    float s = aux ? aux[(long)row * auxLd] : 1.f;
                    ((float*)Cv)[ci] += s * val;
                } else if (mode == 5) {
                    if (row < cnt) {
                        int tok = idx[row];
                        ((float*)Cv)[(long)tok * ldc + col] += aux[(long)tok * auxLd] * val;
                    }
                } else if (mode == 7) {
                    float other = __shfl_xor(val, 1, 64);
                    if (!(lane & 1)) {
                        float g = val, u = other;
                        ((bf16*)Cv)[(long)row * auxLd + (col >> 1)] =
                            (bf16)(g / (1.f + expf(-g)) * u);
                    }
                } else {  // 6: f16 triple [hi|hi|lo]
                    f16 h = (f16)val; f16 l = (f16)(val - (float)h);
                    ((f16*)Cv)[ci] = h; ((f16*)Cv)[ci + auxLd] = h; ((f16*)Cv)[ci + 2 * auxLd] = l;
                }
            }
        }
    }
}

// ---------------------------------------------------------------------------
// RMSNorm -> bf16 out + optional f32 raw copy (MoE entry).
__global__ __launch_bounds__(256) void rmsnorm_kernel(const float* __restrict__ in,
                                                      const float* __restrict__ w,
                                                      bf16* __restrict__ outB,
                                                      float* __restrict__ copyOut, int C) {
    long row = blockIdx.x;
    const float* r = in + row * C;
    float ss = 0.f;
    for (int i = threadIdx.x; i < C; i += 256) { float v = r[i]; ss += v * v; }
    for (int off = 32; off > 0; off >>= 1) ss += __shfl_down(ss, off, 64);
    __shared__ float red[5];
    int lane = threadIdx.x & 63, wv = threadIdx.x >> 6;
    if (lane == 0) red[wv] = ss;
    __syncthreads();
    if (threadIdx.x == 0) red[4] = rsqrtf((red[0] + red[1] + red[2] + red[3]) / C + RMS_EPS);
    __syncthreads();
    float sc = red[4];
    for (int i = threadIdx.x; i < C; i += 256) {
        outB[row * C + i] = (bf16)(r[i] * sc * w[i]);
        if (copyOut) copyOut[row * C + i] = r[i];
    }
}

// RMSNorm -> f16 triple A-pattern [hi|hi|lo] of 64*v, row length 3C.
__global__ __launch_bounds__(256) void rmsnorm3h_kernel(const float* __restrict__ in,
                                                        const float* __restrict__ w,
                                                        f16* __restrict__ out3, int C) {
    long row = blockIdx.x;
    const float* r = in + row * C;
    float ss = 0.f;
    for (int i = threadIdx.x; i < C; i += 256) { float v = r[i]; ss += v * v; }
    for (int off = 32; off > 0; off >>= 1) ss += __shfl_down(ss, off, 64);
    __shared__ float red[5];
    int lane = threadIdx.x & 63, wv = threadIdx.x >> 6;
    if (lane == 0) red[wv] = ss;
    __syncthreads();
    if (threadIdx.x == 0) red[4] = rsqrtf((red[0] + red[1] + red[2] + red[3]) / C + RMS_EPS);
    __syncthreads();
    float sc = red[4];
    f16* o = out3 + row * (3L * C);
    for (int i = threadIdx.x; i < C; i += 256) {
        f16 h, l; split64(r[i] * sc * w[i], h, l);
        o[i] = h; o[C + i] = h; o[2 * C + i] = l;
    }
}

// ---------------------------------------------------------------------------
// ckv (T x 640) -> kvc3 f16 triple A-pattern (3*512), krope f32 (roped)
__global__ __launch_bounds__(256) void kvsplit3h_kernel(const float* __restrict__ ckv,
                                                        const float* __restrict__ nrm,
                                                        const float* __restrict__ freq,
                                                        f16* __restrict__ kvc3,
                                                        float* __restrict__ krope) {
    int t = blockIdx.x; int s = t & (SEQ - 1);
    const float* r = ckv + (long)t * KVDP;
    float ss = 0.f;
    for (int i = threadIdx.x; i < KVCD; i += 256) { float v = r[i]; ss += v * v; }
    for (int off = 32; off > 0; off >>= 1) ss += __shfl_down(ss, off, 64);
    __shared__ float red[5];
    int lane = threadIdx.x & 63, wv = threadIdx.x >> 6;
    if (lane == 0) red[wv] = ss;
    __syncthreads();
    if (threadIdx.x == 0) red[4] = rsqrtf((red[0] + red[1] + red[2] + red[3]) / KVCD + RMS_EPS);
    __syncthreads();
    float sc = red[4];
    f16* o = kvc3 + (long)t * (3 * KVCD);
    for (int i = threadIdx.x; i < KVCD; i += 256) {
        f16 h, l; split64(r[i] * sc * nrm[i], h, l);
        o[i] = h; o[KVCD + i] = h; o[2 * KVCD + i] = l;
    }
    if (threadIdx.x < 32) {
        int i = threadIdx.x;
        float f = freq[s * 32 + i], c = cosf(f), sn = sinf(f);
        float x1 = r[KVCD + 2 * i], x2 = r[KVCD + 2 * i + 1];
        krope[(long)t * ROPED + 2 * i]     = x1 * c - x2 * sn;
        krope[(long)t * ROPED + 2 * i + 1] = x1 * sn + x2 * c;
    }
}

// ---------------------------------------------------------------------------
// qpre (T x 3072 f32) -> q3 (b*16+h, s, 576) f16 triple A-pattern, rope on [128,192)
__global__ __launch_bounds__(256) void build_q3h_kernel(const float* __restrict__ qpre,
                                                        const float* __restrict__ freq,
                                                        f16* __restrict__ q3) {
    int t = blockIdx.x; int b = t >> 10, s = t & (SEQ - 1);
    for (int idx = threadIdx.x; idx < NHEADS * 96; idx += 256) {
        int h = idx / 96, j = idx % 96;
        const float* qrow = qpre + (long)t * 3072 + h * QDIM;
        f16* dst = q3 + ((long)(b * NHEADS + h) * SEQ + s) * (3 * QDIM);
        if (j < 64) {
            int d = 2 * j;
#pragma unroll
            for (int u = 0; u < 2; u++) {
                f16 hh, ll; split64(qrow[d + u], hh, ll);
                dst[d + u] = hh; dst[QDIM + d + u] = hh; dst[2 * QDIM + d + u] = ll;
            }
        } else {
            int i = j - 64;
            float f = freq[s * 32 + i], c = cosf(f), sn = sinf(f);
            float x1 = qrow[NOPED + 2 * i], x2 = qrow[NOPED + 2 * i + 1];
            float v0 = x1 * c - x2 * sn, v1 = x1 * sn + x2 * c;
            int d = NOPED + 2 * i;
            f16 h0, l0, h1, l1; split64(v0, h0, l0); split64(v1, h1, l1);
            dst[d] = h0; dst[QDIM + d] = h0; dst[2 * QDIM + d] = l0;
            dst[d + 1] = h1; dst[QDIM + d + 1] = h1; dst[2 * QDIM + d + 1] = l1;
        }
    }
}

// kv (T x 4096) + krope -> k3 (B-pattern, 576), v3T (b*16+h, d, 3*SEQ) B-pattern
__global__ __launch_bounds__(256) void build_k3h_kernel(const float* __restrict__ kv,
                                                        const float* __restrict__ krope,
                                                        f16* __restrict__ k3,
                                                        f16* __restrict__ v3T) {
    int t = blockIdx.x; int b = t >> 10, s = t & (SEQ - 1);
    const float* kvrow = kv + (long)t * 4096;
    const float* kr = krope + (long)t * ROPED;
    for (int idx = threadIdx.x; idx < NHEADS * 96; idx += 256) {
        int h = idx / 96, j = idx % 96;
        f16* dst = k3 + ((long)(b * NHEADS + h) * SEQ + s) * (3 * QDIM);
        float v0, v1; int d;
        if (j < 64) { d = 2 * j; v0 = kvrow[h * 256 + d]; v1 = kvrow[h * 256 + d + 1]; }
        else { int i = j - 64; d = NOPED + 2 * i; v0 = kr[2 * i]; v1 = kr[2 * i + 1]; }
        f16 h0, l0, h1, l1; split64(v0, h0, l0); split64(v1, h1, l1);
        dst[d] = h0; dst[QDIM + d] = l0; dst[2 * QDIM + d] = h0;
        dst[d + 1] = h1; dst[QDIM + d + 1] = l1; dst[2 * QDIM + d + 1] = h1;
    }
    for (int idx = threadIdx.x; idx < NHEADS * VHD; idx += 256) {
        int h = idx >> 7, d = idx & 127;
        f16 hh, ll; split64(kvrow[h * 256 + NOPED + d], hh, ll);
        long base = ((long)(b * NHEADS + h) * VHD + d) * (3 * SEQ) + s;
        v3T[base] = hh; v3T[base + SEQ] = ll; v3T[base + 2 * SEQ] = hh;
    }
}

// ---------------------------------------------------------------------------
// softmax: P3 row = f16 triple A-pattern of 64*softmax(scores*scale + mask)
__global__ __launch_bounds__(256) void softmax3h_kernel(const float* __restrict__ scores,
                                                        const float* __restrict__ mask,
                                                        f16* __restrict__ P3, float scale) {
    int s = blockIdx.x, h = blockIdx.y;
    const float* row  = scores + ((long)h * SEQ + s) * SEQ;
    const float* mrow = mask + (long)s * SEQ;
    f16* prow = P3 + ((long)h * SEQ + s) * (3 * SEQ);
    float v[4]; float m = -1e30f;
#pragma unroll
    for (int j = 0; j < 4; j++) {
        int i = threadIdx.x + j * 256;
        v[j] = row[i] * scale + mrow[i];
        m = fmaxf(m, v[j]);
    }
    for (int off = 32; off > 0; off >>= 1) m = fmaxf(m, __shfl_down(m, off, 64));
    __shared__ float redm[5], reds[5];
    int lane = threadIdx.x & 63, wv = threadIdx.x >> 6;
    if (lane == 0) redm[wv] = m;
    __syncthreads();
    if (threadIdx.x == 0) redm[4] = fmaxf(fmaxf(redm[0], redm[1]), fmaxf(redm[2], redm[3]));
    __syncthreads();
    float M = redm[4];
    float sum = 0.f;
#pragma unroll
    for (int j = 0; j < 4; j++) { v[j] = expf(v[j] - M); sum += v[j]; }
    for (int off = 32; off > 0; off >>= 1) sum += __shfl_down(sum, off, 64);
    if (lane == 0) reds[wv] = sum;
    __syncthreads();
    if (threadIdx.x == 0) reds[4] = reds[0] + reds[1] + reds[2] + reds[3];
    __syncthreads();
    float inv = 1.f / reds[4];
#pragma unroll
    for (int j = 0; j < 4; j++) {
        int i = threadIdx.x + j * 256;
        f16 hh, ll; split64(v[j] * inv, hh, ll);
        prow[i] = hh; prow[SEQ + i] = hh; prow[2 * SEQ + i] = ll;
    }
}

// ---------------------------------------------------------------------------
__global__ void zero_counts_kernel(int* counts) {
    if (threadIdx.x < 8) counts[threadIdx.x] = 0;
}

// router (f32): logits from rmsnorm(x2)*w_ffn @ W_r; softmax; top2 -> wts + lists.
__global__ __launch_bounds__(64) void router_kernel(const float* __restrict__ x2,
                                                    const float* __restrict__ wffn,
                                                    const float* __restrict__ Wr,
                                                    float* __restrict__ wts,
                                                    int* __restrict__ perm,
                                                    int* __restrict__ counts) {
    int t = blockIdx.x; int lane = threadIdx.x;
    const float* r = x2 + (long)t * HIDD;
    float ss = 0.f;
    for (int k = lane; k < HIDD; k += 64) { float v = r[k]; ss += v * v; }
    for (int off = 32; off > 0; off >>= 1) ss += __shfl_down(ss, off, 64);
    float sc = rsqrtf(__shfl(ss, 0, 64) / HIDD + RMS_EPS);
    float acc[8] = {0, 0, 0, 0, 0, 0, 0, 0};
    for (int k = lane; k < HIDD; k += 64) {
        float tv = r[k] * sc * wffn[k];
        const float* wr = Wr + (long)k * 8;
#pragma unroll
        for (int e = 0; e < 8; e++) acc[e] += tv * wr[e];
    }
#pragma unroll
    for (int e = 0; e < 8; e++)
        for (int off = 32; off > 0; off >>= 1) acc[e] += __shfl_down(acc[e], off, 64);
    if (lane == 0) {
        float m = acc[0];
#pragma unroll
        for (int e = 1; e < 8; e++) m = fmaxf(m, acc[e]);
        float p[8]; float se = 0.f;
#pragma unroll
        for (int e = 0; e < 8; e++) { p[e] = expf(acc[e] - m); se += p[e]; }
        float inv = 1.f / se;
        int i1 = 0; float v1 = p[0];
        for (int e = 1; e < 8; e++) if (p[e] > v1) { v1 = p[e]; i1 = e; }
        int i2 = -1; float v2 = -1.f;
        for (int e = 0; e < 8; e++) if (e != i1 && p[e] > v2) { v2 = p[e]; i2 = e; }
#pragma unroll
        for (int e = 0; e < 8; e++)
            wts[(long)t * 8 + e] = (e == i1) ? v1 * inv : ((e == i2) ? v2 * inv : 0.f);
        int s1 = atomicAdd(&counts[i1], 1); perm[i1 * TOK + s1] = t;
        int s2 = atomicAdd(&counts[i2], 1); perm[i2 * TOK + s2] = t;
    }
}

// batched gather (all 8 experts): tA8[e][row] = tbuf[perm[e][row]] (zeros in pad)
__global__ __launch_bounds__(256) void gather8_kernel(const bf16* __restrict__ tbuf,
                                                      const int* __restrict__ perm,
                                                      const int* __restrict__ counts,
                                                      bf16* __restrict__ tA8) {
    int e = blockIdx.y, row = blockIdx.x;
    int cnt = counts[e];
    int pad = (cnt + 127) & ~127;
    if (row >= pad) return;
    bf16* tA = tA8 + (size_t)e * TOK * HIDD;
    int i = threadIdx.x * 8;
    if (row < cnt) {
        int tok = perm[e * TOK + row];
        *(bf16x8*)&tA[(long)row * HIDD + i] = *(const bf16x8*)&tbuf[(long)tok * HIDD + i];
    } else {
        bf16x8 z = {};
        *(bf16x8*)&tA[(long)row * HIDD + i] = z;
    }
}

// ---------------------------------------------------------------------------
static inline size_t alignup(size_t v) { return (v + 255) & ~(size_t)255; }

extern "C" void kernel_launch(void* const* d_in, const int* in_sizes, int n_in,
                              void* d_out, int out_size, void* d_ws, size_t ws_size,
                              hipStream_t stream) {
    const float* x       = (const float*)d_in[0];
    const float* freq    = (const float*)d_in[1];
    const float* mask    = (const float*)d_in[2];
    const float* w_attn  = (const float*)d_in[3];
    const float* w_ffn   = (const float*)d_in[4];
    const float* W_dq    = (const float*)d_in[5];
    const float* q_c_nrm = (const float*)d_in[6];
    const float* W_uq    = (const float*)d_in[7];
    const float* W_dkv   = (const float*)d_in[8];
    const float* kv_nrm  = (const float*)d_in[9];
    const float* W_ukv   = (const float*)d_in[10];
    const float* W_o     = (const float*)d_in[11];
    const float* W_r     = (const float*)d_in[12];
    const float* Ws_gate = (const float*)d_in[13];
    const float* Ws_up   = (const float*)d_in[14];
    const float* Ws_down = (const float*)d_in[15];
    const float* We_gate = (const float*)d_in[16];
    const float* We_up   = (const float*)d_in[17];
    const float* We_down = (const float*)d_in[18];
    float* out = (float*)d_out;
    char* ws = (char*)d_ws;
    (void)in_sizes; (void)n_in; (void)out_size;

    // ---- workspace layout (~350 MB; known budget >= 378 MB) ----
    size_t o = 0;
    auto alloc = [&](size_t n) { size_t r = o; o += alignup(n); return r; };
    size_t oWslot = alloc((size_t)3072 * 3 * QCD * 2);       // 28.3 MB rotating slot
    size_t oQ3    = alloc((size_t)32 * SEQ * 3 * QDIM * 2);
    size_t oK3    = alloc((size_t)32 * SEQ * 3 * QDIM * 2);
    size_t oV3T   = alloc((size_t)32 * VHD * 3 * SEQ * 2);
    size_t oAttn3 = alloc((size_t)TOK * 3 * HIDD * 2);
    size_t oX2    = alloc((size_t)TOK * HIDD * 4);
    size_t oTbuf  = alloc((size_t)TOK * HIDD * 2);
    size_t oWts   = alloc((size_t)TOK * 8 * 4);
    size_t oPerm  = alloc((size_t)8 * TOK * 4);
    size_t oCnt   = alloc((size_t)8 * 4);
    size_t oKrope = alloc((size_t)TOK * ROPED * 4);
    // overlay arena: early chain | scores+P3 (16-head chunk) | tA8+hid (MoE)
    size_t zH3   = alignup((size_t)TOK * 3 * HIDD * 2);
    size_t zCqp  = alignup((size_t)TOK * QCD * 4);
    size_t zCq3  = alignup((size_t)TOK * 3 * QCD * 2);
    size_t zQp   = alignup((size_t)TOK * 3072 * 4);
    size_t zCkv  = alignup((size_t)TOK * KVDP * 4);
    size_t zKvc3 = alignup((size_t)TOK * 3 * KVCD * 2);
    size_t zKv   = alignup((size_t)TOK * 4096 * 4);
    size_t chain = zH3 + zCqp + zCq3 + zQp + zCkv + zKvc3 + zKv;
    size_t zScores = alignup((size_t)16 * SEQ * SEQ * 4);       // 67.1 MB
    size_t zP3     = alignup((size_t)16 * SEQ * 3 * SEQ * 2);   // 100.7 MB
    size_t zTA8    = alignup((size_t)8 * TOK * HIDD * 2);       // 67.1 MB
    size_t zHid    = alignup((size_t)TOK * INTERD * 2);
    size_t arenaSz = chain;
    if (zScores + zP3 > arenaSz) arenaSz = zScores + zP3;
    if (zTA8 + zHid > arenaSz) arenaSz = zTA8 + zHid;
    size_t oArena = alloc(arenaSz);
    if (ws_size < o) return;

    size_t oH3   = oArena;
    size_t oCqp  = oH3 + zH3;
    size_t oCq3  = oCqp + zCqp;
    size_t oQp   = oCq3 + zCq3;
    size_t oCkv  = oQp + zQp;
    size_t oKvc3 = oCkv + zCkv;
    size_t oKv   = oKvc3 + zKvc3;
    size_t oScores = oArena;
    size_t oP3     = oArena + zScores;
    size_t oTA8    = oArena;
    size_t oHid    = oArena + zTA8;

    f16*  wslotH = (f16*)(ws + oWslot);                            // attn f16 triple
    bf16* wslotB = (bf16*)(ws + oWslot);                           // MoE interleaved GU bf16
    bf16* wslotB2 = (bf16*)(ws + oWslot + (size_t)GUD * HIDD * 2); // MoE down bf16
    f16*  q3    = (f16*)(ws + oQ3);
    f16*  k3    = (f16*)(ws + oK3);
    f16*  v3T   = (f16*)(ws + oV3T);
    f16*  attn3 = (f16*)(ws + oAttn3);
    float* x2   = (float*)(ws + oX2);
    bf16* tbuf  = (bf16*)(ws + oTbuf);
    float* wts  = (float*)(ws + oWts);
    int*  perm  = (int*)(ws + oPerm);
    int*  counts = (int*)(ws + oCnt);
    float* krope = (float*)(ws + oKrope);
    f16*  h3    = (f16*)(ws + oH3);
    float* cqpre = (float*)(ws + oCqp);
    f16*  cq3   = (f16*)(ws + oCq3);
    float* qpre = (float*)(ws + oQp);
    float* ckv  = (float*)(ws + oCkv);
    f16*  kvc3  = (f16*)(ws + oKvc3);
    float* kv   = (float*)(ws + oKv);
    float* scores = (float*)(ws + oScores);
    f16*  P3    = (f16*)(ws + oP3);
    bf16* tA8   = (bf16*)(ws + oTA8);
    bf16* hid   = (bf16*)(ws + oHid);

    auto tconv3h = [&](const float* src, f16* dst, int K, int N, int Npad) {
        dim3 g((Npad + 31) / 32, (K + 31) / 32);
        tconv3h_kernel<<<g, 256, 0, stream>>>(src, dst, K, N, Npad);
    };
    auto tconvEx = [&](const float* gate, const float* up, const float* down) {
        tconv_ex3_kernel<<<dim3(64, 64, 3), 256, 0, stream>>>(gate, up, down, wslotB, wslotB2);
    };
    // fp16 GEMM launchers by tile shape
    auto gH128x128 = [&](const f16* A, const f16* B, void* C, const float* aux,
                         int M, int N, int K, int lda, int ldb, int ldc,
                         long sA, long sB, long sC, int Z, int mode, int auxLd, float osc) {
        dim3 g(N / 128, M / 128, Z);
        gemm_bt_kernel<1, 128, 128><<<g, 256, 0, stream>>>((const u16*)A, (const u16*)B, C, aux,
            nullptr, nullptr, K, lda, ldb, ldc, sA, sB, sC, mode, auxLd, osc);
    };
    auto gH128x64 = [&](const f16* A, const f16* B, void* C, const float* aux,
                        int M, int N, int K, int lda, int ldb, int ldc,
                        long sA, long sB, long sC, int Z, int mode, int auxLd, float osc) {
        dim3 g(N / 64, M / 128, Z);
        gemm_bt_kernel<1, 128, 64><<<g, 256, 0, stream>>>((const u16*)A, (const u16*)B, C, aux,
            nullptr, nullptr, K, lda, ldb, ldc, sA, sB, sC, mode, auxLd, osc);
    };
    auto gH64x64 = [&](const f16* A, const f16* B, void* C, const float* aux,
                       int M, int N, int K, int lda, int ldb, int ldc,
                       long sA, long sB, long sC, int Z, int mode, int auxLd, float osc) {
        dim3 g(N / 64, M / 64, Z);
        gemm_bt_kernel<1, 64, 64><<<g, 256, 0, stream>>>((const u16*)A, (const u16*)B, C, aux,
            nullptr, nullptr, K, lda, ldb, ldc, sA, sB, sC, mode, auxLd, osc);
    };
    auto gB128x64 = [&](const bf16* A, const bf16* B, void* C,
                        const float* aux, const int* idx, const int* cnt,
                        int M, int N, int K, int lda, int ldb, int ldc, int mode, int auxLd) {
        dim3 g(N / 64, M / 128, 1);
        gemm_bt_kernel<0, 128, 64><<<g, 256, 0, stream>>>((const u16*)A, (const u16*)B, C, aux,
            idx, cnt, K, lda, ldb, ldc, 0, 0, 0, mode, auxLd, 1.0f);
    };
    auto gB64x64 = [&](const bf16* A, const bf16* B, void* C,
                       const float* aux, const int* idx, const int* cnt,
                       int M, int N, int K, int lda, int ldb, int ldc, int mode, int auxLd) {
        dim3 g(N / 64, M / 64, 1);
        gemm_bt_kernel<0, 64, 64><<<g, 256, 0, stream>>>((const u16*)A, (const u16*)B, C, aux,
            idx, cnt, K, lda, ldb, ldc, 0, 0, 0, mode, auxLd, 1.0f);
    };

    // ---- attention pipeline (split-fp16 3K-concat GEMMs) ----
    rmsnorm3h_kernel<<<TOK, 256, 0, stream>>>(x, w_attn, h3, HIDD);

    tconv3h(W_dq, wslotH, HIDD, QCD, QCD);
    gH128x64(h3, wslotH, cqpre, nullptr, TOK, QCD, 3 * HIDD, 3 * HIDD, 3 * HIDD, QCD,
             0, 0, 0, 1, 0, 0, OSC);
    rmsnorm3h_kernel<<<TOK, 256, 0, stream>>>(cqpre, q_c_nrm, cq3, QCD);

    tconv3h(W_uq, wslotH, QCD, 3072, 3072);
    gH128x64(cq3, wslotH, qpre, nullptr, TOK, 3072, 3 * QCD, 3 * QCD, 3 * QCD, 3072,
             0, 0, 0, 1, 0, 0, OSC);

    tconv3h(W_dkv, wslotH, HIDD, KVD, KVDP);
    gH64x64(h3, wslotH, ckv, nullptr, TOK, KVDP, 3 * HIDD, 3 * HIDD, 3 * HIDD, KVDP,
            0, 0, 0, 1, 0, 0, OSC);
    kvsplit3h_kernel<<<TOK, 256, 0, stream>>>(ckv, kv_nrm, freq, kvc3, krope);

    tconv3h(W_ukv, wslotH, KVCD, 4096, 4096);
    gH128x128(kvc3, wslotH, kv, nullptr, TOK, 4096, 3 * KVCD, 3 * KVCD, 3 * KVCD, 4096,
              0, 0, 0, 1, 0, 0, OSC);

    build_q3h_kernel<<<TOK, 256, 0, stream>>>(qpre, freq, q3);
    build_k3h_kernel<<<TOK, 256, 0, stream>>>(kv, krope, k3, v3T);

    for (int b = 0; b < 2; b++) {
        int h0 = b * NHEADS;
        gH128x128(q3 + (size_t)h0 * SEQ * 3 * QDIM, k3 + (size_t)h0 * SEQ * 3 * QDIM,
                  scores, nullptr, SEQ, SEQ, 3 * QDIM, 3 * QDIM, 3 * QDIM, SEQ,
                  (long)SEQ * 3 * QDIM, (long)SEQ * 3 * QDIM, (long)SEQ * SEQ, 16, 0, 0, OSC);
        softmax3h_kernel<<<dim3(SEQ, 16), 256, 0, stream>>>(scores, mask, P3,
                                                            1.f / sqrtf((float)QDIM));
        // PV: acc = 4096*P*V; store triple of 64*(P*V) -> osc = 1/64
        gH64x64(P3, v3T + (size_t)h0 * VHD * 3 * SEQ,
                attn3 + (size_t)b * SEQ * 3 * HIDD, nullptr,
                SEQ, VHD, 3 * SEQ, 3 * SEQ, 3 * SEQ, 3 * HIDD,
                (long)SEQ * 3 * SEQ, (long)VHD * 3 * SEQ, (long)VHD, 16, 6, HIDD,
                1.0f / SPS);
    }

    tconv3h(W_o, wslotH, HIDD, HIDD, HIDD);
    gH128x64(attn3, wslotH, x2, x, TOK, HIDD, 3 * HIDD, 3 * HIDD, 3 * HIDD, HIDD,
             0, 0, 0, 1, 2, HIDD, OSC);

    // ---- MoE ----
    rmsnorm_kernel<<<TOK, 256, 0, stream>>>(x2, w_ffn, tbuf, out, HIDD);  // out = x2
    zero_counts_kernel<<<1, 64, 0, stream>>>(counts);
    router_kernel<<<TOK, 64, 0, stream>>>(x2, w_ffn, W_r, wts, perm, counts);
    gather8_kernel<<<dim3(TOK, 8), 256, 0, stream>>>(tbuf, perm, counts, tA8);

    // shared experts (dense): fused silu GU -> hid, then down accumulate
    for (int e = 0; e < 2; e++) {
        tconvEx(Ws_gate + (size_t)e * HIDD * INTERD,
                Ws_up   + (size_t)e * HIDD * INTERD,
                Ws_down + (size_t)e * INTERD * HIDD);
        gB128x64(tbuf, wslotB, hid, nullptr, nullptr, nullptr,
                 TOK, GUD, HIDD, HIDD, HIDD, GUD, 7, INTERD);
        gB128x64(hid, wslotB2, out, nullptr, nullptr, nullptr,
                 TOK, HIDD, INTERD, INTERD, INTERD, HIDD, 3, 0);
    }
    // routed experts (top-2 sparse)
    for (int e = 0; e < 8; e++) {
        tconvEx(We_gate + (size_t)e * HIDD * INTERD,
                We_up   + (size_t)e * HIDD * INTERD,
                We_down + (size_t)e * INTERD * HIDD);
        gB64x64(tA8 + (size_t)e * TOK * HIDD, wslotB, hid, nullptr, nullptr, counts + e,
                TOK, GUD, HIDD, HIDD, HIDD, GUD, 7, INTERD);
        gB64x64(hid, wslotB2, out, wts + e, perm + (size_t)e * TOK, counts + e,
                TOK, HIDD, INTERD, INTERD, INTERD, HIDD, 5, 8);
    }
}

// Round 10
// 1612.237 us; speedup vs baseline: 1.0604x; 1.0604x over previous
//
#include <hip/hip_runtime.h>

typedef __bf16 bf16;
typedef _Float16 f16;
typedef unsigned short u16;
typedef __bf16 bf16x8 __attribute__((ext_vector_type(8)));
typedef _Float16 f16x8 __attribute__((ext_vector_type(8)));
typedef unsigned short u16x8 __attribute__((ext_vector_type(8)));
typedef float f32x4 __attribute__((ext_vector_type(4)));

#define TOK   2048   // B*S
#define SEQ   1024
#define HIDD  2048
#define NHEADS 16
#define QCD   1536
#define KVCD  512
#define ROPED 64
#define NOPED 128
#define QDIM  192    // NOPE+ROPE
#define VHD   128
#define KVD   576
#define KVDP  640
#define INTERD 1408
#define GUD   2816   // 2*INTER
#define RMS_EPS 1e-6f
#define SPS   64.0f          // split pre-scale (both operands)
#define OSC   (1.0f/4096.0f) // epilogue descale (64*64)

__device__ inline void split64(float v, f16& h, f16& l) {
    v *= SPS; h = (f16)v; l = (f16)(v - (float)h);
}

__device__ inline void gl_lds16(const void* g, void* l) {
    __builtin_amdgcn_global_load_lds(
        (const __attribute__((address_space(1))) void*)g,
        (__attribute__((address_space(3))) void*)l,
        16, 0, 0);
}

#define WAITN(N) asm volatile("s_waitcnt vmcnt(" #N ")" ::: "memory")

// ---------------------------------------------------------------------------
// Batched expert conversion (gate/up column-INTERLEAVED for fused-silu GEMM):
// z=0: gate n -> dGU row 2n; z=1: up n -> dGU row 2n+1; z=2: down -> dD.
__global__ __launch_bounds__(256) void tconv_ex3_kernel(const float* __restrict__ gate,
                                                        const float* __restrict__ up,
                                                        const float* __restrict__ down,
                                                        bf16* __restrict__ dGU,
                                                        bf16* __restrict__ dD) {
    const float* src; bf16* dst; int K, N, rowMul, rowAdd;
    if (blockIdx.z == 0)      { src = gate; dst = dGU; K = HIDD;   N = INTERD; rowMul = 2; rowAdd = 0; }
    else if (blockIdx.z == 1) { src = up;   dst = dGU; K = HIDD;   N = INTERD; rowMul = 2; rowAdd = 1; }
    else                      { src = down; dst = dD;  K = INTERD; N = HIDD;   rowMul = 1; rowAdd = 0; }
    int nb = blockIdx.x * 32, kb = blockIdx.y * 32;
    if (nb >= N || kb >= K) return;
    __shared__ float tile[32][33];
    int tx = threadIdx.x & 31, ty = threadIdx.x >> 5;
#pragma unroll
    for (int i = 0; i < 32; i += 8)
        tile[ty + i][tx] = src[(long)(kb + ty + i) * N + nb + tx];
    __syncthreads();
#pragma unroll
    for (int i = 0; i < 32; i += 8) {
        int n = nb + ty + i;
        dst[(long)(n * rowMul + rowAdd) * K + kb + tx] = (bf16)tile[tx][ty + i];
    }
}

// Transpose-convert f16 TRIPLE B-pattern [hi|lo|hi] of 64*w: src (K,N) -> dst (Npad,3K).
__global__ __launch_bounds__(256) void tconv3h_kernel(const float* __restrict__ src,
                                                      f16* __restrict__ dst,
                                                      int K, int N, int Npad) {
    __shared__ float tile[32][33];
    int nb = blockIdx.x * 32, kb = blockIdx.y * 32;
    int tx = threadIdx.x & 31, ty = threadIdx.x >> 5;
#pragma unroll
    for (int i = 0; i < 32; i += 8) {
        int k = kb + ty + i, n = nb + tx;
        tile[ty + i][tx] = (k < K && n < N) ? src[(long)k * N + n] : 0.f;
    }
    __syncthreads();
#pragma unroll
    for (int i = 0; i < 32; i += 8) {
        int n = nb + ty + i, k = kb + tx;
        if (n < Npad && k < K) {
            f16 h, l; split64(tile[tx][ty + i], h, l);
            long base = (long)n * (3 * K) + k;
            dst[base] = h; dst[base + K] = l; dst[base + 2 * K] = h;
        }
    }
}

// ---------------------------------------------------------------------------
// NT GEMM, TMxTN tile, BK=64, global_load_lds w16, XOR-swizzled LDS (rule 21),
// counted-vmcnt prefetch pipeline (T4, round-8 proven form): stage FIRST (max
// MLP during the wait), then counted WAITN for the oldest tile, barrier,
// compute, WAR barrier. Never vmcnt(0) in the main loop.
// mode 0: f32 = val*osc; 2: f32 = val*osc + aux[row*auxLd+col];
// mode 3: f32 += (aux?aux[row*auxLd]:1)*val*osc;
// mode 5: scatter f32 out[idx[row]*ldc+col] += aux[idx[row]*auxLd]*val*osc (row<cnt);
// mode 6: f16 triple [hi@ci | hi@ci+auxLd | lo@ci+2auxLd] of val*osc;
// mode 7: fused silu-mul (interleaved g/u cols): even lanes store
//         bf16(silu(g)*u) at Cv[row*auxLd + col/2].
template<int F16, int TM, int TN>
__global__ __launch_bounds__(256) void gemm_bt_kernel(
    const u16* __restrict__ A, const u16* __restrict__ B, void* __restrict__ Cv,
    const float* __restrict__ aux, const int* __restrict__ idx,
    const int* __restrict__ cntPtr,
    int K, int lda, int ldb, int ldc,
    long sA, long sB, long sC,
    int mode, int auxLd, float osc)
{
    constexpr int AM = TM / 32;
    constexpr int AN = TN / 32;
    constexpr int NBUF = (TM + TN > 192) ? 2 : 3;
    constexpr int PF = NBUF - 1;
    constexpr int L = TM / 32 + TN / 32;            // gl_lds loads per wave per stage
    __shared__ u16 As[NBUF][TM * 64];
    __shared__ u16 Bs[NBUF][TN * 64];
    const int bn = blockIdx.x, bm = blockIdx.y, z = blockIdx.z;
    int cnt = 1 << 30;
    if (cntPtr) {
        cnt = *cntPtr;
        int pad = (cnt + TM - 1) & ~(TM - 1);
        if (bm * TM >= pad) return;
    }
    const int tid = threadIdx.x, lane = tid & 63, w = tid >> 6;
    const int wm = w >> 1, wn = w & 1;
    const int lr = lane & 15;
    const int srow = lane >> 3, c16 = lane & 7;   // staging: 8 rows x 8 granules
    const u16* Ab = A + (long)z * sA + (long)bm * TM * lda;
    const u16* Bb = B + (long)z * sB + (long)bn * TN * ldb;
    f32x4 acc[AM][AN] = {};

    auto stage = [&](int buf, int k0) {
#pragma unroll
        for (int i = 0; i < TM / 32; i++) {
            int rb = i * 32 + w * 8;               // wave-uniform LDS row base
            int row = rb + srow;
            int gc = ((c16 ^ (row & 7)) << 3);     // inverse-swizzled source col
            gl_lds16(&Ab[(long)row * lda + k0 + gc], &As[buf][rb * 64]);
        }
#pragma unroll
        for (int i = 0; i < TN / 32; i++) {
            int rb = i * 32 + w * 8;
            int row = rb + srow;
            int gc = ((c16 ^ (row & 7)) << 3);
            gl_lds16(&Bb[(long)row * ldb + k0 + gc], &Bs[buf][rb * 64]);
        }
    };
    auto compute = [&](int cur) {
#pragma unroll
        for (int ks = 0; ks < 2; ks++) {
            u16x8 af[AM], bfr[AN];
#pragma unroll
            for (int mi = 0; mi < AM; mi++) {
                int row = wm * (TM / 2) + mi * 16 + lr;
                int cg = (ks * 4 + (lane >> 4)) ^ (row & 7);
                af[mi] = *(const u16x8*)&As[cur][row * 64 + cg * 8];
            }
#pragma unroll
            for (int ni = 0; ni < AN; ni++) {
                int row = wn * (TN / 2) + ni * 16 + lr;
                int cg = (ks * 4 + (lane >> 4)) ^ (row & 7);
                bfr[ni] = *(const u16x8*)&Bs[cur][row * 64 + cg * 8];
            }
#pragma unroll
            for (int mi = 0; mi < AM; mi++)
#pragma unroll
                for (int ni = 0; ni < AN; ni++) {
                    if constexpr (F16)
                        acc[mi][ni] = __builtin_amdgcn_mfma_f32_16x16x32_f16(
                            __builtin_bit_cast(f16x8, af[mi]),
                            __builtin_bit_cast(f16x8, bfr[ni]), acc[mi][ni], 0, 0, 0);
                    else
                        acc[mi][ni] = __builtin_amdgcn_mfma_f32_16x16x32_bf16(
                            __builtin_bit_cast(bf16x8, af[mi]),
                            __builtin_bit_cast(bf16x8, bfr[ni]), acc[mi][ni], 0, 0, 0);
                }
        }
    };

    const int nk = K >> 6;
#pragma unroll
    for (int p = 0; p < PF; ++p) if (p < nk) stage(p, p << 6);

    if constexpr (PF == 2) {
        for (int t = 0; t < nk; ++t) {
            if (t + PF < nk) stage((t + PF) % NBUF, (t + PF) << 6);
            const int inflight = (nk - 1 - t < PF) ? (nk - 1 - t) : PF;
            if (inflight >= 2) {
                if constexpr (L == 4) WAITN(8); else WAITN(12);
            } else if (inflight == 1) {
                if constexpr (L == 4) WAITN(4); else WAITN(6);
            } else {
                WAITN(0);
            }
            __builtin_amdgcn_s_barrier();
            __builtin_amdgcn_sched_barrier(0);
            compute(t % NBUF);
            __builtin_amdgcn_s_barrier();   // WAR: next stage overwrites oldest buffer
        }
    } else {
        for (int t = 0; t < nk; ++t) {
            if (t + 1 < nk) stage((t + 1) & 1, (t + 1) << 6);
            if (t + 1 < nk) WAITN(8);
            else            WAITN(0);
            __builtin_amdgcn_s_barrier();
            __builtin_amdgcn_sched_barrier(0);
            compute(t & 1);
            __builtin_amdgcn_s_barrier();
        }
    }

    const int r0 = (lane >> 4) << 2;
    const int rowBase = bm * TM + wm * (TM / 2);
    const int colBase = bn * TN + wn * (TN / 2);
#pragma unroll
    for (int mi = 0; mi < AM; mi++) {
#pragma unroll
        for (int ni = 0; ni < AN; ni++) {
#pragma unroll
            for (int r = 0; r < 4; r++) {
                int row = rowBase + mi * 16 + r0 + r;
                int col = colBase + ni * 16 + lr;
                float val = acc[mi][ni][r] * osc;
                long ci = (long)z * sC + (long)row * ldc + col;
                if (mode == 0) {
                    ((float*)Cv)[ci] = val;
                } else if (mode == 2) {
                    ((float*)Cv)[ci] = val + aux[(long)row * auxLd + col];
                } else if (mode == 3) {
                    float s = aux ? aux[(long)row * auxLd] : 1.f;
                    ((float*)Cv)[ci] += s * val;
                } else if (mode == 5) {
                    if (row < cnt) {
                        int tok = idx[row];
                        ((float*)Cv)[(long)tok * ldc + col] += aux[(long)tok * auxLd] * val;
                    }
                } else if (mode == 7) {
                    float other = __shfl_xor(val, 1, 64);
                    if (!(lane & 1)) {
                        float g = val, u = other;
                        ((bf16*)Cv)[(long)row * auxLd + (col >> 1)] =
                            (bf16)(g / (1.f + expf(-g)) * u);
                    }
                } else {  // 6: f16 triple [hi|hi|lo]
                    f16 h = (f16)val; f16 l = (f16)(val - (float)h);
                    ((f16*)Cv)[ci] = h; ((f16*)Cv)[ci + auxLd] = h; ((f16*)Cv)[ci + 2 * auxLd] = l;
                }
            }
        }
    }
}

// ---------------------------------------------------------------------------
// RMSNorm -> bf16 out + optional f32 raw copy (MoE entry).
__global__ __launch_bounds__(256) void rmsnorm_kernel(const float* __restrict__ in,
                                                      const float* __restrict__ w,
                                                      bf16* __restrict__ outB,
                                                      float* __restrict__ copyOut, int C) {
    long row = blockIdx.x;
    const float* r = in + row * C;
    float ss = 0.f;
    for (int i = threadIdx.x; i < C; i += 256) { float v = r[i]; ss += v * v; }
    for (int off = 32; off > 0; off >>= 1) ss += __shfl_down(ss, off, 64);
    __shared__ float red[5];
    int lane = threadIdx.x & 63, wv = threadIdx.x >> 6;
    if (lane == 0) red[wv] = ss;
    __syncthreads();
    if (threadIdx.x == 0) red[4] = rsqrtf((red[0] + red[1] + red[2] + red[3]) / C + RMS_EPS);
    __syncthreads();
    float sc = red[4];
    for (int i = threadIdx.x; i < C; i += 256) {
        outB[row * C + i] = (bf16)(r[i] * sc * w[i]);
        if (copyOut) copyOut[row * C + i] = r[i];
    }
}

// RMSNorm -> f16 triple A-pattern [hi|hi|lo] of 64*v, row length 3C.
__global__ __launch_bounds__(256) void rmsnorm3h_kernel(const float* __restrict__ in,
                                                        const float* __restrict__ w,
                                                        f16* __restrict__ out3, int C) {
    long row = blockIdx.x;
    const float* r = in + row * C;
    float ss = 0.f;
    for (int i = threadIdx.x; i < C; i += 256) { float v = r[i]; ss += v * v; }
    for (int off = 32; off > 0; off >>= 1) ss += __shfl_down(ss, off, 64);
    __shared__ float red[5];
    int lane = threadIdx.x & 63, wv = threadIdx.x >> 6;
    if (lane == 0) red[wv] = ss;
    __syncthreads();
    if (threadIdx.x == 0) red[4] = rsqrtf((red[0] + red[1] + red[2] + red[3]) / C + RMS_EPS);
    __syncthreads();
    float sc = red[4];
    f16* o = out3 + row * (3L * C);
    for (int i = threadIdx.x; i < C; i += 256) {
        f16 h, l; split64(r[i] * sc * w[i], h, l);
        o[i] = h; o[C + i] = h; o[2 * C + i] = l;
    }
}

// ---------------------------------------------------------------------------
// ckv (T x 640) -> kvc3 f16 triple A-pattern (3*512), krope f32 (roped)
__global__ __launch_bounds__(256) void kvsplit3h_kernel(const float* __restrict__ ckv,
                                                        const float* __restrict__ nrm,
                                                        const float* __restrict__ freq,
                                                        f16* __restrict__ kvc3,
                                                        float* __restrict__ krope) {
    int t = blockIdx.x; int s = t & (SEQ - 1);
    const float* r = ckv + (long)t * KVDP;
    float ss = 0.f;
    for (int i = threadIdx.x; i < KVCD; i += 256) { float v = r[i]; ss += v * v; }
    for (int off = 32; off > 0; off >>= 1) ss += __shfl_down(ss, off, 64);
    __shared__ float red[5];
    int lane = threadIdx.x & 63, wv = threadIdx.x >> 6;
    if (lane == 0) red[wv] = ss;
    __syncthreads();
    if (threadIdx.x == 0) red[4] = rsqrtf((red[0] + red[1] + red[2] + red[3]) / KVCD + RMS_EPS);
    __syncthreads();
    float sc = red[4];
    f16* o = kvc3 + (long)t * (3 * KVCD);
    for (int i = threadIdx.x; i < KVCD; i += 256) {
        f16 h, l; split64(r[i] * sc * nrm[i], h, l);
        o[i] = h; o[KVCD + i] = h; o[2 * KVCD + i] = l;
    }
    if (threadIdx.x < 32) {
        int i = threadIdx.x;
        float f = freq[s * 32 + i], c = cosf(f), sn = sinf(f);
        float x1 = r[KVCD + 2 * i], x2 = r[KVCD + 2 * i + 1];
        krope[(long)t * ROPED + 2 * i]     = x1 * c - x2 * sn;
        krope[(long)t * ROPED + 2 * i + 1] = x1 * sn + x2 * c;
    }
}

// ---------------------------------------------------------------------------
// qpre (T x 3072 f32) -> q3 (b*16+h, s, 576) f16 triple A-pattern, rope on [128,192)
__global__ __launch_bounds__(256) void build_q3h_kernel(const float* __restrict__ qpre,
                                                        const float* __restrict__ freq,
                                                        f16* __restrict__ q3) {
    int t = blockIdx.x; int b = t >> 10, s = t & (SEQ - 1);
    for (int idx = threadIdx.x; idx < NHEADS * 96; idx += 256) {
        int h = idx / 96, j = idx % 96;
        const float* qrow = qpre + (long)t * 3072 + h * QDIM;
        f16* dst = q3 + ((long)(b * NHEADS + h) * SEQ + s) * (3 * QDIM);
        if (j < 64) {
            int d = 2 * j;
#pragma unroll
            for (int u = 0; u < 2; u++) {
                f16 hh, ll; split64(qrow[d + u], hh, ll);
                dst[d + u] = hh; dst[QDIM + d + u] = hh; dst[2 * QDIM + d + u] = ll;
            }
        } else {
            int i = j - 64;
            float f = freq[s * 32 + i], c = cosf(f), sn = sinf(f);
            float x1 = qrow[NOPED + 2 * i], x2 = qrow[NOPED + 2 * i + 1];
            float v0 = x1 * c - x2 * sn, v1 = x1 * sn + x2 * c;
            int d = NOPED + 2 * i;
            f16 h0, l0, h1, l1; split64(v0, h0, l0); split64(v1, h1, l1);
            dst[d] = h0; dst[QDIM + d] = h0; dst[2 * QDIM + d] = l0;
            dst[d + 1] = h1; dst[QDIM + d + 1] = h1; dst[2 * QDIM + d + 1] = l1;
        }
    }
}

// kv (T x 4096) + krope -> k3 (B-pattern, 576), v3T (b*16+h, d, 3*SEQ) B-pattern
__global__ __launch_bounds__(256) void build_k3h_kernel(const float* __restrict__ kv,
                                                        const float* __restrict__ krope,
                                                        f16* __restrict__ k3,
                                                        f16* __restrict__ v3T) {
    int t = blockIdx.x; int b = t >> 10, s = t & (SEQ - 1);
    const float* kvrow = kv + (long)t * 4096;
    const float* kr = krope + (long)t * ROPED;
    for (int idx = threadIdx.x; idx < NHEADS * 96; idx += 256) {
        int h = idx / 96, j = idx % 96;
        f16* dst = k3 + ((long)(b * NHEADS + h) * SEQ + s) * (3 * QDIM);
        float v0, v1; int d;
        if (j < 64) { d = 2 * j; v0 = kvrow[h * 256 + d]; v1 = kvrow[h * 256 + d + 1]; }
        else { int i = j - 64; d = NOPED + 2 * i; v0 = kr[2 * i]; v1 = kr[2 * i + 1]; }
        f16 h0, l0, h1, l1; split64(v0, h0, l0); split64(v1, h1, l1);
        dst[d] = h0; dst[QDIM + d] = l0; dst[2 * QDIM + d] = h0;
        dst[d + 1] = h1; dst[QDIM + d + 1] = l1; dst[2 * QDIM + d + 1] = h1;
    }
    for (int idx = threadIdx.x; idx < NHEADS * VHD; idx += 256) {
        int h = idx >> 7, d = idx & 127;
        f16 hh, ll; split64(kvrow[h * 256 + NOPED + d], hh, ll);
        long base = ((long)(b * NHEADS + h) * VHD + d) * (3 * SEQ) + s;
        v3T[base] = hh; v3T[base + SEQ] = ll; v3T[base + 2 * SEQ] = hh;
    }
}

// ---------------------------------------------------------------------------
// softmax: P3 row = f16 triple A-pattern of 64*softmax(scores*scale + mask)
__global__ __launch_bounds__(256) void softmax3h_kernel(const float* __restrict__ scores,
                                                        const float* __restrict__ mask,
                                                        f16* __restrict__ P3, float scale) {
    int s = blockIdx.x, h = blockIdx.y;
    const float* row  = scores + ((long)h * SEQ + s) * SEQ;
    const float* mrow = mask + (long)s * SEQ;
    f16* prow = P3 + ((long)h * SEQ + s) * (3 * SEQ);
    float v[4]; float m = -1e30f;
#pragma unroll
    for (int j = 0; j < 4; j++) {
        int i = threadIdx.x + j * 256;
        v[j] = row[i] * scale + mrow[i];
        m = fmaxf(m, v[j]);
    }
    for (int off = 32; off > 0; off >>= 1) m = fmaxf(m, __shfl_down(m, off, 64));
    __shared__ float redm[5], reds[5];
    int lane = threadIdx.x & 63, wv = threadIdx.x >> 6;
    if (lane == 0) redm[wv] = m;
    __syncthreads();
    if (threadIdx.x == 0) redm[4] = fmaxf(fmaxf(redm[0], redm[1]), fmaxf(redm[2], redm[3]));
    __syncthreads();
    float M = redm[4];
    float sum = 0.f;
#pragma unroll
    for (int j = 0; j < 4; j++) { v[j] = expf(v[j] - M); sum += v[j]; }
    for (int off = 32; off > 0; off >>= 1) sum += __shfl_down(sum, off, 64);
    if (lane == 0) reds[wv] = sum;
    __syncthreads();
    if (threadIdx.x == 0) reds[4] = reds[0] + reds[1] + reds[2] + reds[3];
    __syncthreads();
    float inv = 1.f / reds[4];
#pragma unroll
    for (int j = 0; j < 4; j++) {
        int i = threadIdx.x + j * 256;
        f16 hh, ll; split64(v[j] * inv, hh, ll);
        prow[i] = hh; prow[SEQ + i] = hh; prow[2 * SEQ + i] = ll;
    }
}

// ---------------------------------------------------------------------------
__global__ void zero_counts_kernel(int* counts) {
    if (threadIdx.x < 8) counts[threadIdx.x] = 0;
}

// router (f32): logits from rmsnorm(x2)*w_ffn @ W_r; softmax; top2 -> wts + lists.
__global__ __launch_bounds__(64) void router_kernel(const float* __restrict__ x2,
                                                    const float* __restrict__ wffn,
                                                    const float* __restrict__ Wr,
                                                    float* __restrict__ wts,
                                                    int* __restrict__ perm,
                                                    int* __restrict__ counts) {
    int t = blockIdx.x; int lane = threadIdx.x;
    const float* r = x2 + (long)t * HIDD;
    float ss = 0.f;
    for (int k = lane; k < HIDD; k += 64) { float v = r[k]; ss += v * v; }
    for (int off = 32; off > 0; off >>= 1) ss += __shfl_down(ss, off, 64);
    float sc = rsqrtf(__shfl(ss, 0, 64) / HIDD + RMS_EPS);
    float acc[8] = {0, 0, 0, 0, 0, 0, 0, 0};
    for (int k = lane; k < HIDD; k += 64) {
        float tv = r[k] * sc * wffn[k];
        const float* wr = Wr + (long)k * 8;
#pragma unroll
        for (int e = 0; e < 8; e++) acc[e] += tv * wr[e];
    }
#pragma unroll
    for (int e = 0; e < 8; e++)
        for (int off = 32; off > 0; off >>= 1) acc[e] += __shfl_down(acc[e], off, 64);
    if (lane == 0) {
        float m = acc[0];
#pragma unroll
        for (int e = 1; e < 8; e++) m = fmaxf(m, acc[e]);
        float p[8]; float se = 0.f;
#pragma unroll
        for (int e = 0; e < 8; e++) { p[e] = expf(acc[e] - m); se += p[e]; }
        float inv = 1.f / se;
        int i1 = 0; float v1 = p[0];
        for (int e = 1; e < 8; e++) if (p[e] > v1) { v1 = p[e]; i1 = e; }
        int i2 = -1; float v2 = -1.f;
        for (int e = 0; e < 8; e++) if (e != i1 && p[e] > v2) { v2 = p[e]; i2 = e; }
#pragma unroll
        for (int e = 0; e < 8; e++)
            wts[(long)t * 8 + e] = (e == i1) ? v1 * inv : ((e == i2) ? v2 * inv : 0.f);
        int s1 = atomicAdd(&counts[i1], 1); perm[i1 * TOK + s1] = t;
        int s2 = atomicAdd(&counts[i2], 1); perm[i2 * TOK + s2] = t;
    }
}

// batched gather (all 8 experts): tA8[e][row] = tbuf[perm[e][row]] (zeros in pad)
__global__ __launch_bounds__(256) void gather8_kernel(const bf16* __restrict__ tbuf,
                                                      const int* __restrict__ perm,
                                                      const int* __restrict__ counts,
                                                      bf16* __restrict__ tA8) {
    int e = blockIdx.y, row = blockIdx.x;
    int cnt = counts[e];
    int pad = (cnt + 127) & ~127;
    if (row >= pad) return;
    bf16* tA = tA8 + (size_t)e * TOK * HIDD;
    int i = threadIdx.x * 8;
    if (row < cnt) {
        int tok = perm[e * TOK + row];
        *(bf16x8*)&tA[(long)row * HIDD + i] = *(const bf16x8*)&tbuf[(long)tok * HIDD + i];
    } else {
        bf16x8 z = {};
        *(bf16x8*)&tA[(long)row * HIDD + i] = z;
    }
}

// ---------------------------------------------------------------------------
static inline size_t alignup(size_t v) { return (v + 255) & ~(size_t)255; }

extern "C" void kernel_launch(void* const* d_in, const int* in_sizes, int n_in,
                              void* d_out, int out_size, void* d_ws, size_t ws_size,
                              hipStream_t stream) {
    const float* x       = (const float*)d_in[0];
    const float* freq    = (const float*)d_in[1];
    const float* mask    = (const float*)d_in[2];
    const float* w_attn  = (const float*)d_in[3];
    const float* w_ffn   = (const float*)d_in[4];
    const float* W_dq    = (const float*)d_in[5];
    const float* q_c_nrm = (const float*)d_in[6];
    const float* W_uq    = (const float*)d_in[7];
    const float* W_dkv   = (const float*)d_in[8];
    const float* kv_nrm  = (const float*)d_in[9];
    const float* W_ukv   = (const float*)d_in[10];
    const float* W_o     = (const float*)d_in[11];
    const float* W_r     = (const float*)d_in[12];
    const float* Ws_gate = (const float*)d_in[13];
    const float* Ws_up   = (const float*)d_in[14];
    const float* Ws_down = (const float*)d_in[15];
    const float* We_gate = (const float*)d_in[16];
    const float* We_up   = (const float*)d_in[17];
    const float* We_down = (const float*)d_in[18];
    float* out = (float*)d_out;
    char* ws = (char*)d_ws;
    (void)in_sizes; (void)n_in; (void)out_size;

    // ---- workspace layout (~350 MB; known budget >= 378 MB) ----
    size_t o = 0;
    auto alloc = [&](size_t n) { size_t r = o; o += alignup(n); return r; };
    size_t oWslot = alloc((size_t)3072 * 3 * QCD * 2);       // 28.3 MB rotating slot
    size_t oQ3    = alloc((size_t)32 * SEQ * 3 * QDIM * 2);
    size_t oK3    = alloc((size_t)32 * SEQ * 3 * QDIM * 2);
    size_t oV3T   = alloc((size_t)32 * VHD * 3 * SEQ * 2);
    size_t oAttn3 = alloc((size_t)TOK * 3 * HIDD * 2);
    size_t oX2    = alloc((size_t)TOK * HIDD * 4);
    size_t oTbuf  = alloc((size_t)TOK * HIDD * 2);
    size_t oWts   = alloc((size_t)TOK * 8 * 4);
    size_t oPerm  = alloc((size_t)8 * TOK * 4);
    size_t oCnt   = alloc((size_t)8 * 4);
    size_t oKrope = alloc((size_t)TOK * ROPED * 4);
    // overlay arena: early chain | scores+P3 (16-head chunk) | tA8+hid (MoE)
    size_t zH3   = alignup((size_t)TOK * 3 * HIDD * 2);
    size_t zCqp  = alignup((size_t)TOK * QCD * 4);
    size_t zCq3  = alignup((size_t)TOK * 3 * QCD * 2);
    size_t zQp   = alignup((size_t)TOK * 3072 * 4);
    size_t zCkv  = alignup((size_t)TOK * KVDP * 4);
    size_t zKvc3 = alignup((size_t)TOK * 3 * KVCD * 2);
    size_t zKv   = alignup((size_t)TOK * 4096 * 4);
    size_t chain = zH3 + zCqp + zCq3 + zQp + zCkv + zKvc3 + zKv;
    size_t zScores = alignup((size_t)16 * SEQ * SEQ * 4);       // 67.1 MB
    size_t zP3     = alignup((size_t)16 * SEQ * 3 * SEQ * 2);   // 100.7 MB
    size_t zTA8    = alignup((size_t)8 * TOK * HIDD * 2);       // 67.1 MB
    size_t zHid    = alignup((size_t)TOK * INTERD * 2);
    size_t arenaSz = chain;
    if (zScores + zP3 > arenaSz) arenaSz = zScores + zP3;
    if (zTA8 + zHid > arenaSz) arenaSz = zTA8 + zHid;
    size_t oArena = alloc(arenaSz);
    if (ws_size < o) return;

    size_t oH3   = oArena;
    size_t oCqp  = oH3 + zH3;
    size_t oCq3  = oCqp + zCqp;
    size_t oQp   = oCq3 + zCq3;
    size_t oCkv  = oQp + zQp;
    size_t oKvc3 = oCkv + zCkv;
    size_t oKv   = oKvc3 + zKvc3;
    size_t oScores = oArena;
    size_t oP3     = oArena + zScores;
    size_t oTA8    = oArena;
    size_t oHid    = oArena + zTA8;

    f16*  wslotH = (f16*)(ws + oWslot);                            // attn f16 triple
    bf16* wslotB = (bf16*)(ws + oWslot);                           // MoE interleaved GU bf16
    bf16* wslotB2 = (bf16*)(ws + oWslot + (size_t)GUD * HIDD * 2); // MoE down bf16
    f16*  q3    = (f16*)(ws + oQ3);
    f16*  k3    = (f16*)(ws + oK3);
    f16*  v3T   = (f16*)(ws + oV3T);
    f16*  attn3 = (f16*)(ws + oAttn3);
    float* x2   = (float*)(ws + oX2);
    bf16* tbuf  = (bf16*)(ws + oTbuf);
    float* wts  = (float*)(ws + oWts);
    int*  perm  = (int*)(ws + oPerm);
    int*  counts = (int*)(ws + oCnt);
    float* krope = (float*)(ws + oKrope);
    f16*  h3    = (f16*)(ws + oH3);
    float* cqpre = (float*)(ws + oCqp);
    f16*  cq3   = (f16*)(ws + oCq3);
    float* qpre = (float*)(ws + oQp);
    float* ckv  = (float*)(ws + oCkv);
    f16*  kvc3  = (f16*)(ws + oKvc3);
    float* kv   = (float*)(ws + oKv);
    float* scores = (float*)(ws + oScores);
    f16*  P3    = (f16*)(ws + oP3);
    bf16* tA8   = (bf16*)(ws + oTA8);
    bf16* hid   = (bf16*)(ws + oHid);

    auto tconv3h = [&](const float* src, f16* dst, int K, int N, int Npad) {
        dim3 g((Npad + 31) / 32, (K + 31) / 32);
        tconv3h_kernel<<<g, 256, 0, stream>>>(src, dst, K, N, Npad);
    };
    auto tconvEx = [&](const float* gate, const float* up, const float* down) {
        tconv_ex3_kernel<<<dim3(64, 64, 3), 256, 0, stream>>>(gate, up, down, wslotB, wslotB2);
    };
    // fp16 GEMM launchers by tile shape
    auto gH128x128 = [&](const f16* A, const f16* B, void* C, const float* aux,
                         int M, int N, int K, int lda, int ldb, int ldc,
                         long sA, long sB, long sC, int Z, int mode, int auxLd, float osc) {
        dim3 g(N / 128, M / 128, Z);
        gemm_bt_kernel<1, 128, 128><<<g, 256, 0, stream>>>((const u16*)A, (const u16*)B, C, aux,
            nullptr, nullptr, K, lda, ldb, ldc, sA, sB, sC, mode, auxLd, osc);
    };
    auto gH128x64 = [&](const f16* A, const f16* B, void* C, const float* aux,
                        int M, int N, int K, int lda, int ldb, int ldc,
                        long sA, long sB, long sC, int Z, int mode, int auxLd, float osc) {
        dim3 g(N / 64, M / 128, Z);
        gemm_bt_kernel<1, 128, 64><<<g, 256, 0, stream>>>((const u16*)A, (const u16*)B, C, aux,
            nullptr, nullptr, K, lda, ldb, ldc, sA, sB, sC, mode, auxLd, osc);
    };
    auto gH64x64 = [&](const f16* A, const f16* B, void* C, const float* aux,
                       int M, int N, int K, int lda, int ldb, int ldc,
                       long sA, long sB, long sC, int Z, int mode, int auxLd, float osc) {
        dim3 g(N / 64, M / 64, Z);
        gemm_bt_kernel<1, 64, 64><<<g, 256, 0, stream>>>((const u16*)A, (const u16*)B, C, aux,
            nullptr, nullptr, K, lda, ldb, ldc, sA, sB, sC, mode, auxLd, osc);
    };
    auto gB128x64 = [&](const bf16* A, const bf16* B, void* C,
                        const float* aux, const int* idx, const int* cnt,
                        int M, int N, int K, int lda, int ldb, int ldc, int mode, int auxLd) {
        dim3 g(N / 64, M / 128, 1);
        gemm_bt_kernel<0, 128, 64><<<g, 256, 0, stream>>>((const u16*)A, (const u16*)B, C, aux,
            idx, cnt, K, lda, ldb, ldc, 0, 0, 0, mode, auxLd, 1.0f);
    };
    auto gB64x64 = [&](const bf16* A, const bf16* B, void* C,
                       const float* aux, const int* idx, const int* cnt,
                       int M, int N, int K, int lda, int ldb, int ldc, int mode, int auxLd) {
        dim3 g(N / 64, M / 64, 1);
        gemm_bt_kernel<0, 64, 64><<<g, 256, 0, stream>>>((const u16*)A, (const u16*)B, C, aux,
            idx, cnt, K, lda, ldb, ldc, 0, 0, 0, mode, auxLd, 1.0f);
    };

    // ---- attention pipeline (split-fp16 3K-concat GEMMs) ----
    rmsnorm3h_kernel<<<TOK, 256, 0, stream>>>(x, w_attn, h3, HIDD);

    tconv3h(W_dq, wslotH, HIDD, QCD, QCD);
    gH128x64(h3, wslotH, cqpre, nullptr, TOK, QCD, 3 * HIDD, 3 * HIDD, 3 * HIDD, QCD,
             0, 0, 0, 1, 0, 0, OSC);
    rmsnorm3h_kernel<<<TOK, 256, 0, stream>>>(cqpre, q_c_nrm, cq3, QCD);

    tconv3h(W_uq, wslotH, QCD, 3072, 3072);
    gH128x128(cq3, wslotH, qpre, nullptr, TOK, 3072, 3 * QCD, 3 * QCD, 3 * QCD, 3072,
              0, 0, 0, 1, 0, 0, OSC);

    tconv3h(W_dkv, wslotH, HIDD, KVD, KVDP);
    gH64x64(h3, wslotH, ckv, nullptr, TOK, KVDP, 3 * HIDD, 3 * HIDD, 3 * HIDD, KVDP,
            0, 0, 0, 1, 0, 0, OSC);
    kvsplit3h_kernel<<<TOK, 256, 0, stream>>>(ckv, kv_nrm, freq, kvc3, krope);

    tconv3h(W_ukv, wslotH, KVCD, 4096, 4096);
    gH128x128(kvc3, wslotH, kv, nullptr, TOK, 4096, 3 * KVCD, 3 * KVCD, 3 * KVCD, 4096,
              0, 0, 0, 1, 0, 0, OSC);

    build_q3h_kernel<<<TOK, 256, 0, stream>>>(qpre, freq, q3);
    build_k3h_kernel<<<TOK, 256, 0, stream>>>(kv, krope, k3, v3T);

    for (int b = 0; b < 2; b++) {
        int h0 = b * NHEADS;
        gH128x128(q3 + (size_t)h0 * SEQ * 3 * QDIM, k3 + (size_t)h0 * SEQ * 3 * QDIM,
                  scores, nullptr, SEQ, SEQ, 3 * QDIM, 3 * QDIM, 3 * QDIM, SEQ,
                  (long)SEQ * 3 * QDIM, (long)SEQ * 3 * QDIM, (long)SEQ * SEQ, 16, 0, 0, OSC);
        softmax3h_kernel<<<dim3(SEQ, 16), 256, 0, stream>>>(scores, mask, P3,
                                                            1.f / sqrtf((float)QDIM));
        // PV: acc = 4096*P*V; store triple of 64*(P*V) -> osc = 1/64
        gH64x64(P3, v3T + (size_t)h0 * VHD * 3 * SEQ,
                attn3 + (size_t)b * SEQ * 3 * HIDD, nullptr,
                SEQ, VHD, 3 * SEQ, 3 * SEQ, 3 * SEQ, 3 * HIDD,
                (long)SEQ * 3 * SEQ, (long)VHD * 3 * SEQ, (long)VHD, 16, 6, HIDD,
                1.0f / SPS);
    }

    tconv3h(W_o, wslotH, HIDD, HIDD, HIDD);
    gH128x64(attn3, wslotH, x2, x, TOK, HIDD, 3 * HIDD, 3 * HIDD, 3 * HIDD, HIDD,
             0, 0, 0, 1, 2, HIDD, OSC);

    // ---- MoE ----
    rmsnorm_kernel<<<TOK, 256, 0, stream>>>(x2, w_ffn, tbuf, out, HIDD);  // out = x2
    zero_counts_kernel<<<1, 64, 0, stream>>>(counts);
    router_kernel<<<TOK, 64, 0, stream>>>(x2, w_ffn, W_r, wts, perm, counts);
    gather8_kernel<<<dim3(TOK, 8), 256, 0, stream>>>(tbuf, perm, counts, tA8);

    // shared experts (dense): fused silu GU -> hid, then down accumulate
    for (int e = 0; e < 2; e++) {
        tconvEx(Ws_gate + (size_t)e * HIDD * INTERD,
                Ws_up   + (size_t)e * HIDD * INTERD,
                Ws_down + (size_t)e * INTERD * HIDD);
        gB128x64(tbuf, wslotB, hid, nullptr, nullptr, nullptr,
                 TOK, GUD, HIDD, HIDD, HIDD, GUD, 7, INTERD);
        gB128x64(hid, wslotB2, out, nullptr, nullptr, nullptr,
                 TOK, HIDD, INTERD, INTERD, INTERD, HIDD, 3, 0);
    }
    // routed experts (top-2 sparse)
    for (int e = 0; e < 8; e++) {
        tconvEx(We_gate + (size_t)e * HIDD * INTERD,
                We_up   + (size_t)e * HIDD * INTERD,
                We_down + (size_t)e * INTERD * HIDD);
        gB64x64(tA8 + (size_t)e * TOK * HIDD, wslotB, hid, nullptr, nullptr, counts + e,
                TOK, GUD, HIDD, HIDD, HIDD, GUD, 7, INTERD);
        gB64x64(hid, wslotB2, out, wts + e, perm + (size_t)e * TOK, counts + e,
                TOK, HIDD, INTERD, INTERD, INTERD, HIDD, 5, 8);
    }
}

// Round 11
// 1390.198 us; speedup vs baseline: 1.2298x; 1.1597x over previous
//
#include <hip/hip_runtime.h>

typedef __bf16 bf16;
typedef _Float16 f16;
typedef unsigned short u16;
typedef __bf16 bf16x8 __attribute__((ext_vector_type(8)));
typedef _Float16 f16x8 __attribute__((ext_vector_type(8)));
typedef unsigned short u16x8 __attribute__((ext_vector_type(8)));
typedef float f32x4 __attribute__((ext_vector_type(4)));

#define TOK   2048   // B*S
#define SEQ   1024
#define HIDD  2048
#define NHEADS 16
#define QCD   1536
#define KVCD  512
#define ROPED 64
#define NOPED 128
#define QDIM  192    // NOPE+ROPE
#define VHD   128
#define KVD   576
#define KVDP  640
#define INTERD 1408
#define GUD   2816   // 2*INTER
#define RMS_EPS 1e-6f
#define SPS   64.0f          // split pre-scale (both operands)
#define OSC   (1.0f/4096.0f) // epilogue descale (64*64)

__device__ inline void split64(float v, f16& h, f16& l) {
    v *= SPS; h = (f16)v; l = (f16)(v - (float)h);
}

__device__ inline void gl_lds16(const void* g, void* l) {
    __builtin_amdgcn_global_load_lds(
        (const __attribute__((address_space(1))) void*)g,
        (__attribute__((address_space(3))) void*)l,
        16, 0, 0);
}

#define WAITN(N) asm volatile("s_waitcnt vmcnt(" #N ")" ::: "memory")

// ---------------------------------------------------------------------------
// Shared-expert conversion (gate/up column-INTERLEAVED for fused-silu GEMM):
// z=0: gate n -> dGU row 2n; z=1: up n -> dGU row 2n+1; z=2: down -> dD.
__global__ __launch_bounds__(256) void tconv_ex3_kernel(const float* __restrict__ gate,
                                                        const float* __restrict__ up,
                                                        const float* __restrict__ down,
                                                        bf16* __restrict__ dGU,
                                                        bf16* __restrict__ dD) {
    const float* src; bf16* dst; int K, N, rowMul, rowAdd;
    if (blockIdx.z == 0)      { src = gate; dst = dGU; K = HIDD;   N = INTERD; rowMul = 2; rowAdd = 0; }
    else if (blockIdx.z == 1) { src = up;   dst = dGU; K = HIDD;   N = INTERD; rowMul = 2; rowAdd = 1; }
    else                      { src = down; dst = dD;  K = INTERD; N = HIDD;   rowMul = 1; rowAdd = 0; }
    int nb = blockIdx.x * 32, kb = blockIdx.y * 32;
    if (nb >= N || kb >= K) return;
    __shared__ float tile[32][33];
    int tx = threadIdx.x & 31, ty = threadIdx.x >> 5;
#pragma unroll
    for (int i = 0; i < 32; i += 8)
        tile[ty + i][tx] = src[(long)(kb + ty + i) * N + nb + tx];
    __syncthreads();
#pragma unroll
    for (int i = 0; i < 32; i += 8) {
        int n = nb + ty + i;
        dst[(long)(n * rowMul + rowAdd) * K + kb + tx] = (bf16)tile[tx][ty + i];
    }
}

// All routed GU weights in one launch: z = expert*2 + isUp (z in [0,16)).
__global__ __launch_bounds__(256) void tconv_guall_kernel(const float* __restrict__ gate,
                                                          const float* __restrict__ up,
                                                          bf16* __restrict__ dstAll) {
    int e = blockIdx.z >> 1, isUp = blockIdx.z & 1;
    const float* src = (isUp ? up : gate) + (size_t)e * HIDD * INTERD;
    bf16* dst = dstAll + (size_t)e * GUD * HIDD;
    int nb = blockIdx.x * 32, kb = blockIdx.y * 32;   // N=INTERD, K=HIDD
    __shared__ float tile[32][33];
    int tx = threadIdx.x & 31, ty = threadIdx.x >> 5;
#pragma unroll
    for (int i = 0; i < 32; i += 8)
        tile[ty + i][tx] = src[(long)(kb + ty + i) * INTERD + nb + tx];
    __syncthreads();
#pragma unroll
    for (int i = 0; i < 32; i += 8) {
        int n = nb + ty + i;
        dst[(long)(n * 2 + isUp) * HIDD + kb + tx] = (bf16)tile[tx][ty + i];
    }
}

// All routed down weights in one launch: z = expert.
__global__ __launch_bounds__(256) void tconv_downall_kernel(const float* __restrict__ down,
                                                            bf16* __restrict__ dstAll) {
    int e = blockIdx.z;
    const float* src = down + (size_t)e * INTERD * HIDD;
    bf16* dst = dstAll + (size_t)e * HIDD * INTERD;
    int nb = blockIdx.x * 32, kb = blockIdx.y * 32;   // N=HIDD, K=INTERD
    __shared__ float tile[32][33];
    int tx = threadIdx.x & 31, ty = threadIdx.x >> 5;
#pragma unroll
    for (int i = 0; i < 32; i += 8)
        tile[ty + i][tx] = src[(long)(kb + ty + i) * HIDD + nb + tx];
    __syncthreads();
#pragma unroll
    for (int i = 0; i < 32; i += 8)
        dst[(long)(nb + ty + i) * INTERD + kb + tx] = (bf16)tile[tx][ty + i];
}

// Transpose-convert f16 TRIPLE B-pattern [hi|lo|hi] of 64*w: src (K,N) -> dst (Npad,3K).
__global__ __launch_bounds__(256) void tconv3h_kernel(const float* __restrict__ src,
                                                      f16* __restrict__ dst,
                                                      int K, int N, int Npad) {
    __shared__ float tile[32][33];
    int nb = blockIdx.x * 32, kb = blockIdx.y * 32;
    int tx = threadIdx.x & 31, ty = threadIdx.x >> 5;
#pragma unroll
    for (int i = 0; i < 32; i += 8) {
        int k = kb + ty + i, n = nb + tx;
        tile[ty + i][tx] = (k < K && n < N) ? src[(long)k * N + n] : 0.f;
    }
    __syncthreads();
#pragma unroll
    for (int i = 0; i < 32; i += 8) {
        int n = nb + ty + i, k = kb + tx;
        if (n < Npad && k < K) {
            f16 h, l; split64(tile[tx][ty + i], h, l);
            long base = (long)n * (3 * K) + k;
            dst[base] = h; dst[base + K] = l; dst[base + 2 * K] = h;
        }
    }
}

// ---------------------------------------------------------------------------
// NT GEMM, TMxTN tile, BK=64, global_load_lds w16, XOR-swizzled LDS (rule 21),
// counted-vmcnt prefetch pipeline (T4, round-8 proven form): stage FIRST (max
// MLP during the wait), then counted WAITN for the oldest tile, barrier,
// compute, WAR barrier. Never vmcnt(0) in the main loop.
// Grouped-z support: cnt = cntPtr[z]; mode-5 uses idx[z*TOK+row], aux[tok*auxLd+z];
// mode-7 A-side row indirection through idx (preloaded to regs) when idx!=null.
// mode 0: f32 = val*osc; 2: f32 = val*osc + aux[row*auxLd+col];
// mode 3: f32 += (aux?aux[row*auxLd]:1)*val*osc;
// mode 5: scatter atomicAdd out[idx[zT+row]*ldc+col] += aux[tok*auxLd+z]*val (row<cnt);
// mode 6: f16 triple [hi@ci | hi@ci+auxLd | lo@ci+2auxLd] of val*osc;
// mode 7: fused silu-mul (interleaved g/u cols): even lanes store
//         bf16(silu(g)*u) at Cv[z*sC + row*auxLd + col/2].
template<int F16, int TM, int TN>
__global__ __launch_bounds__(256) void gemm_bt_kernel(
    const u16* __restrict__ A, const u16* __restrict__ B, void* __restrict__ Cv,
    const float* __restrict__ aux, const int* __restrict__ idx,
    const int* __restrict__ cntPtr,
    int K, int lda, int ldb, int ldc,
    long sA, long sB, long sC,
    int mode, int auxLd, float osc)
{
    constexpr int AM = TM / 32;
    constexpr int AN = TN / 32;
    constexpr int NBUF = (TM + TN > 192) ? 2 : 3;
    constexpr int PF = NBUF - 1;
    constexpr int L = TM / 32 + TN / 32;            // gl_lds loads per wave per stage
    __shared__ u16 As[NBUF][TM * 64];
    __shared__ u16 Bs[NBUF][TN * 64];
    const int bn = blockIdx.x, bm = blockIdx.y, z = blockIdx.z;
    int cnt = 1 << 30;
    if (cntPtr) {
        cnt = cntPtr[z];
        int pad = (cnt + TM - 1) & ~(TM - 1);
        if (bm * TM >= pad) return;
    }
    const int tid = threadIdx.x, lane = tid & 63, w = tid >> 6;
    const int wm = w >> 1, wn = w & 1;
    const int lr = lane & 15;
    const int srow = lane >> 3, c16 = lane & 7;   // staging: 8 rows x 8 granules
    const u16* Ab = A + (long)z * sA + (long)bm * TM * lda;
    const u16* Bb = B + (long)z * sB + (long)bn * TN * ldb;
    f32x4 acc[AM][AN] = {};

    // A-side row indirection (grouped fused-silu GEMM): preload indices to regs
    const bool aidx = (idx != nullptr && mode == 7);
    int iperm[4];
    if (aidx) {
#pragma unroll
        for (int i = 0; i < TM / 32; i++) {
            int r = bm * TM + i * 32 + w * 8 + srow;
            int v = idx[(long)z * TOK + r];
            iperm[i] = (r < cnt) ? v : 0;
        }
    }

    auto stage = [&](int buf, int k0) {
#pragma unroll
        for (int i = 0; i < TM / 32; i++) {
            int rb = i * 32 + w * 8;               // wave-uniform LDS row base
            int row = rb + srow;
            int gc = ((c16 ^ (row & 7)) << 3);     // inverse-swizzled source col
            const u16* src = aidx ? (A + (long)iperm[i] * lda + k0 + gc)
                                  : (Ab + (long)row * lda + k0 + gc);
            gl_lds16(src, &As[buf][rb * 64]);
        }
#pragma unroll
        for (int i = 0; i < TN / 32; i++) {
            int rb = i * 32 + w * 8;
            int row = rb + srow;
            int gc = ((c16 ^ (row & 7)) << 3);
            gl_lds16(&Bb[(long)row * ldb + k0 + gc], &Bs[buf][rb * 64]);
        }
    };
    auto compute = [&](int cur) {
#pragma unroll
        for (int ks = 0; ks < 2; ks++) {
            u16x8 af[AM], bfr[AN];
#pragma unroll
            for (int mi = 0; mi < AM; mi++) {
                int row = wm * (TM / 2) + mi * 16 + lr;
                int cg = (ks * 4 + (lane >> 4)) ^ (row & 7);
                af[mi] = *(const u16x8*)&As[cur][row * 64 + cg * 8];
            }
#pragma unroll
            for (int ni = 0; ni < AN; ni++) {
                int row = wn * (TN / 2) + ni * 16 + lr;
                int cg = (ks * 4 + (lane >> 4)) ^ (row & 7);
                bfr[ni] = *(const u16x8*)&Bs[cur][row * 64 + cg * 8];
            }
#pragma unroll
            for (int mi = 0; mi < AM; mi++)
#pragma unroll
                for (int ni = 0; ni < AN; ni++) {
                    if constexpr (F16)
                        acc[mi][ni] = __builtin_amdgcn_mfma_f32_16x16x32_f16(
                            __builtin_bit_cast(f16x8, af[mi]),
                            __builtin_bit_cast(f16x8, bfr[ni]), acc[mi][ni], 0, 0, 0);
                    else
                        acc[mi][ni] = __builtin_amdgcn_mfma_f32_16x16x32_bf16(
                            __builtin_bit_cast(bf16x8, af[mi]),
                            __builtin_bit_cast(bf16x8, bfr[ni]), acc[mi][ni], 0, 0, 0);
                }
        }
    };

    const int nk = K >> 6;
#pragma unroll
    for (int p = 0; p < PF; ++p) if (p < nk) stage(p, p << 6);

    if constexpr (PF == 2) {
        for (int t = 0; t < nk; ++t) {
            if (t + PF < nk) stage((t + PF) % NBUF, (t + PF) << 6);
            const int inflight = (nk - 1 - t < PF) ? (nk - 1 - t) : PF;
            if (inflight >= 2) {
                if constexpr (L == 4) WAITN(8); else WAITN(12);
            } else if (inflight == 1) {
                if constexpr (L == 4) WAITN(4); else WAITN(6);
            } else {
                WAITN(0);
            }
            __builtin_amdgcn_s_barrier();
            __builtin_amdgcn_sched_barrier(0);
            compute(t % NBUF);
            __builtin_amdgcn_s_barrier();   // WAR: next stage overwrites oldest buffer
        }
    } else {
        for (int t = 0; t < nk; ++t) {
            if (t + 1 < nk) stage((t + 1) & 1, (t + 1) << 6);
            if (t + 1 < nk) WAITN(8);
            else            WAITN(0);
            __builtin_amdgcn_s_barrier();
            __builtin_amdgcn_sched_barrier(0);
            compute(t & 1);
            __builtin_amdgcn_s_barrier();
        }
    }

    const int r0 = (lane >> 4) << 2;
    const int rowBase = bm * TM + wm * (TM / 2);
    const int colBase = bn * TN + wn * (TN / 2);
#pragma unroll
    for (int mi = 0; mi < AM; mi++) {
#pragma unroll
        for (int ni = 0; ni < AN; ni++) {
#pragma unroll
            for (int r = 0; r < 4; r++) {
                int row = rowBase + mi * 16 + r0 + r;
                int col = colBase + ni * 16 + lr;
                float val = acc[mi][ni][r] * osc;
                long ci = (long)z * sC + (long)row * ldc + col;
                if (mode == 0) {
                    ((float*)Cv)[ci] = val;
                } else if (mode == 2) {
                    ((float*)Cv)[ci] = val + aux[(long)row * auxLd + col];
                } else if (mode == 3) {
                    float s = aux ? aux[(long)row * auxLd] : 1.f;
                    ((float*)Cv)[ci] += s * val;
                } else if (mode == 5) {
                    if (row < cnt) {
                        int tok = idx[(long)z * TOK + row];
                        atomicAdd(&((float*)Cv)[(long)tok * ldc + col],
                                  aux[(long)tok * auxLd + z] * val);
                    }
                } else if (mode == 7) {
                    float other = __shfl_xor(val, 1, 64);
                    if (!(lane & 1)) {
                        float g = val, u = other;
                        ((bf16*)Cv)[(long)z * sC + (long)row * auxLd + (col >> 1)] =
                            (bf16)(g / (1.f + expf(-g)) * u);
                    }
                } else {  // 6: f16 triple [hi|hi|lo]
                    f16 h = (f16)val; f16 l = (f16)(val - (float)h);
                    ((f16*)Cv)[ci] = h; ((f16*)Cv)[ci + auxLd] = h; ((f16*)Cv)[ci + 2 * auxLd] = l;
                }
            }
        }
    }
}

// ---------------------------------------------------------------------------
// RMSNorm -> bf16 out + optional f32 raw copy (MoE entry).
__global__ __launch_bounds__(256) void rmsnorm_kernel(const float* __restrict__ in,
                                                      const float* __restrict__ w,
                                                      bf16* __restrict__ outB,
                                                      float* __restrict__ copyOut, int C) {
    long row = blockIdx.x;
    const float* r = in + row * C;
    float ss = 0.f;
    for (int i = threadIdx.x; i < C; i += 256) { float v = r[i]; ss += v * v; }
    for (int off = 32; off > 0; off >>= 1) ss += __shfl_down(ss, off, 64);
    __shared__ float red[5];
    int lane = threadIdx.x & 63, wv = threadIdx.x >> 6;
    if (lane == 0) red[wv] = ss;
    __syncthreads();
    if (threadIdx.x == 0) red[4] = rsqrtf((red[0] + red[1] + red[2] + red[3]) / C + RMS_EPS);
    __syncthreads();
    float sc = red[4];
    for (int i = threadIdx.x; i < C; i += 256) {
        outB[row * C + i] = (bf16)(r[i] * sc * w[i]);
        if (copyOut) copyOut[row * C + i] = r[i];
    }
}

// RMSNorm -> f16 triple A-pattern [hi|hi|lo] of 64*v, row length 3C.
__global__ __launch_bounds__(256) void rmsnorm3h_kernel(const float* __restrict__ in,
                                                        const float* __restrict__ w,
                                                        f16* __restrict__ out3, int C) {
    long row = blockIdx.x;
    const float* r = in + row * C;
    float ss = 0.f;
    for (int i = threadIdx.x; i < C; i += 256) { float v = r[i]; ss += v * v; }
    for (int off = 32; off > 0; off >>= 1) ss += __shfl_down(ss, off, 64);
    __shared__ float red[5];
    int lane = threadIdx.x & 63, wv = threadIdx.x >> 6;
    if (lane == 0) red[wv] = ss;
    __syncthreads();
    if (threadIdx.x == 0) red[4] = rsqrtf((red[0] + red[1] + red[2] + red[3]) / C + RMS_EPS);
    __syncthreads();
    float sc = red[4];
    f16* o = out3 + row * (3L * C);
    for (int i = threadIdx.x; i < C; i += 256) {
        f16 h, l; split64(r[i] * sc * w[i], h, l);
        o[i] = h; o[C + i] = h; o[2 * C + i] = l;
    }
}

// ---------------------------------------------------------------------------
// ckv (T x 640) -> kvc3 f16 triple A-pattern (3*512), krope f32 (roped)
__global__ __launch_bounds__(256) void kvsplit3h_kernel(const float* __restrict__ ckv,
                                                        const float* __restrict__ nrm,
                                                        const float* __restrict__ freq,
                                                        f16* __restrict__ kvc3,
                                                        float* __restrict__ krope) {
    int t = blockIdx.x; int s = t & (SEQ - 1);
    const float* r = ckv + (long)t * KVDP;
    float ss = 0.f;
    for (int i = threadIdx.x; i < KVCD; i += 256) { float v = r[i]; ss += v * v; }
    for (int off = 32; off > 0; off >>= 1) ss += __shfl_down(ss, off, 64);
    __shared__ float red[5];
    int lane = threadIdx.x & 63, wv = threadIdx.x >> 6;
    if (lane == 0) red[wv] = ss;
    __syncthreads();
    if (threadIdx.x == 0) red[4] = rsqrtf((red[0] + red[1] + red[2] + red[3]) / KVCD + RMS_EPS);
    __syncthreads();
    float sc = red[4];
    f16* o = kvc3 + (long)t * (3 * KVCD);
    for (int i = threadIdx.x; i < KVCD; i += 256) {
        f16 h, l; split64(r[i] * sc * nrm[i], h, l);
        o[i] = h; o[KVCD + i] = h; o[2 * KVCD + i] = l;
    }
    if (threadIdx.x < 32) {
        int i = threadIdx.x;
        float f = freq[s * 32 + i], c = cosf(f), sn = sinf(f);
        float x1 = r[KVCD + 2 * i], x2 = r[KVCD + 2 * i + 1];
        krope[(long)t * ROPED + 2 * i]     = x1 * c - x2 * sn;
        krope[(long)t * ROPED + 2 * i + 1] = x1 * sn + x2 * c;
    }
}

// ---------------------------------------------------------------------------
// qpre (T x 3072 f32) -> q3 (b*16+h, s, 576) f16 triple A-pattern, rope on [128,192)
__global__ __launch_bounds__(256) void build_q3h_kernel(const float* __restrict__ qpre,
                                                        const float* __restrict__ freq,
                                                        f16* __restrict__ q3) {
    int t = blockIdx.x; int b = t >> 10, s = t & (SEQ - 1);
    for (int idx = threadIdx.x; idx < NHEADS * 96; idx += 256) {
        int h = idx / 96, j = idx % 96;
        const float* qrow = qpre + (long)t * 3072 + h * QDIM;
        f16* dst = q3 + ((long)(b * NHEADS + h) * SEQ + s) * (3 * QDIM);
        if (j < 64) {
            int d = 2 * j;
#pragma unroll
            for (int u = 0; u < 2; u++) {
                f16 hh, ll; split64(qrow[d + u], hh, ll);
                dst[d + u] = hh; dst[QDIM + d + u] = hh; dst[2 * QDIM + d + u] = ll;
            }
        } else {
            int i = j - 64;
            float f = freq[s * 32 + i], c = cosf(f), sn = sinf(f);
            float x1 = qrow[NOPED + 2 * i], x2 = qrow[NOPED + 2 * i + 1];
            float v0 = x1 * c - x2 * sn, v1 = x1 * sn + x2 * c;
            int d = NOPED + 2 * i;
            f16 h0, l0, h1, l1; split64(v0, h0, l0); split64(v1, h1, l1);
            dst[d] = h0; dst[QDIM + d] = h0; dst[2 * QDIM + d] = l0;
            dst[d + 1] = h1; dst[QDIM + d + 1] = h1; dst[2 * QDIM + d + 1] = l1;
        }
    }
}

// kv (T x 4096) + krope -> k3 (B-pattern, 576), v3T (b*16+h, d, 3*SEQ) B-pattern
__global__ __launch_bounds__(256) void build_k3h_kernel(const float* __restrict__ kv,
                                                        const float* __restrict__ krope,
                                                        f16* __restrict__ k3,
                                                        f16* __restrict__ v3T) {
    int t = blockIdx.x; int b = t >> 10, s = t & (SEQ - 1);
    const float* kvrow = kv + (long)t * 4096;
    const float* kr = krope + (long)t * ROPED;
    for (int idx = threadIdx.x; idx < NHEADS * 96; idx += 256) {
        int h = idx / 96, j = idx % 96;
        f16* dst = k3 + ((long)(b * NHEADS + h) * SEQ + s) * (3 * QDIM);
        float v0, v1; int d;
        if (j < 64) { d = 2 * j; v0 = kvrow[h * 256 + d]; v1 = kvrow[h * 256 + d + 1]; }
        else { int i = j - 64; d = NOPED + 2 * i; v0 = kr[2 * i]; v1 = kr[2 * i + 1]; }
        f16 h0, l0, h1, l1; split64(v0, h0, l0); split64(v1, h1, l1);
        dst[d] = h0; dst[QDIM + d] = l0; dst[2 * QDIM + d] = h0;
        dst[d + 1] = h1; dst[QDIM + d + 1] = l1; dst[2 * QDIM + d + 1] = h1;
    }
    for (int idx = threadIdx.x; idx < NHEADS * VHD; idx += 256) {
        int h = idx >> 7, d = idx & 127;
        f16 hh, ll; split64(kvrow[h * 256 + NOPED + d], hh, ll);
        long base = ((long)(b * NHEADS + h) * VHD + d) * (3 * SEQ) + s;
        v3T[base] = hh; v3T[base + SEQ] = ll; v3T[base + 2 * SEQ] = hh;
    }
}

// ---------------------------------------------------------------------------
// softmax: P3 row = f16 triple A-pattern of 64*softmax(scores*scale + mask)
__global__ __launch_bounds__(256) void softmax3h_kernel(const float* __restrict__ scores,
                                                        const float* __restrict__ mask,
                                                        f16* __restrict__ P3, float scale) {
    int s = blockIdx.x, h = blockIdx.y;
    const float* row  = scores + ((long)h * SEQ + s) * SEQ;
    const float* mrow = mask + (long)s * SEQ;
    f16* prow = P3 + ((long)h * SEQ + s) * (3 * SEQ);
    float v[4]; float m = -1e30f;
#pragma unroll
    for (int j = 0; j < 4; j++) {
        int i = threadIdx.x + j * 256;
        v[j] = row[i] * scale + mrow[i];
        m = fmaxf(m, v[j]);
    }
    for (int off = 32; off > 0; off >>= 1) m = fmaxf(m, __shfl_down(m, off, 64));
    __shared__ float redm[5], reds[5];
    int lane = threadIdx.x & 63, wv = threadIdx.x >> 6;
    if (lane == 0) redm[wv] = m;
    __syncthreads();
    if (threadIdx.x == 0) redm[4] = fmaxf(fmaxf(redm[0], redm[1]), fmaxf(redm[2], redm[3]));
    __syncthreads();
    float M = redm[4];
    float sum = 0.f;
#pragma unroll
    for (int j = 0; j < 4; j++) { v[j] = expf(v[j] - M); sum += v[j]; }
    for (int off = 32; off > 0; off >>= 1) sum += __shfl_down(sum, off, 64);
    if (lane == 0) reds[wv] = sum;
    __syncthreads();
    if (threadIdx.x == 0) reds[4] = reds[0] + reds[1] + reds[2] + reds[3];
    __syncthreads();
    float inv = 1.f / reds[4];
#pragma unroll
    for (int j = 0; j < 4; j++) {
        int i = threadIdx.x + j * 256;
        f16 hh, ll; split64(v[j] * inv, hh, ll);
        prow[i] = hh; prow[SEQ + i] = hh; prow[2 * SEQ + i] = ll;
    }
}

// ---------------------------------------------------------------------------
__global__ void zero_counts_kernel(int* counts) {
    if (threadIdx.x < 8) counts[threadIdx.x] = 0;
}

// router (f32): logits from rmsnorm(x2)*w_ffn @ W_r; softmax; top2 -> wts + lists.
__global__ __launch_bounds__(64) void router_kernel(const float* __restrict__ x2,
                                                    const float* __restrict__ wffn,
                                                    const float* __restrict__ Wr,
                                                    float* __restrict__ wts,
                                                    int* __restrict__ perm,
                                                    int* __restrict__ counts) {
    int t = blockIdx.x; int lane = threadIdx.x;
    const float* r = x2 + (long)t * HIDD;
    float ss = 0.f;
    for (int k = lane; k < HIDD; k += 64) { float v = r[k]; ss += v * v; }
    for (int off = 32; off > 0; off >>= 1) ss += __shfl_down(ss, off, 64);
    float sc = rsqrtf(__shfl(ss, 0, 64) / HIDD + RMS_EPS);
    float acc[8] = {0, 0, 0, 0, 0, 0, 0, 0};
    for (int k = lane; k < HIDD; k += 64) {
        float tv = r[k] * sc * wffn[k];
        const float* wr = Wr + (long)k * 8;
#pragma unroll
        for (int e = 0; e < 8; e++) acc[e] += tv * wr[e];
    }
#pragma unroll
    for (int e = 0; e < 8; e++)
        for (int off = 32; off > 0; off >>= 1) acc[e] += __shfl_down(acc[e], off, 64);
    if (lane == 0) {
        float m = acc[0];
#pragma unroll
        for (int e = 1; e < 8; e++) m = fmaxf(m, acc[e]);
        float p[8]; float se = 0.f;
#pragma unroll
        for (int e = 0; e < 8; e++) { p[e] = expf(acc[e] - m); se += p[e]; }
        float inv = 1.f / se;
        int i1 = 0; float v1 = p[0];
        for (int e = 1; e < 8; e++) if (p[e] > v1) { v1 = p[e]; i1 = e; }
        int i2 = -1; float v2 = -1.f;
        for (int e = 0; e < 8; e++) if (e != i1 && p[e] > v2) { v2 = p[e]; i2 = e; }
#pragma unroll
        for (int e = 0; e < 8; e++)
            wts[(long)t * 8 + e] = (e == i1) ? v1 * inv : ((e == i2) ? v2 * inv : 0.f);
        int s1 = atomicAdd(&counts[i1], 1); perm[i1 * TOK + s1] = t;
        int s2 = atomicAdd(&counts[i2], 1); perm[i2 * TOK + s2] = t;
    }
}

// ---------------------------------------------------------------------------
static inline size_t alignup(size_t v) { return (v + 255) & ~(size_t)255; }

extern "C" void kernel_launch(void* const* d_in, const int* in_sizes, int n_in,
                              void* d_out, int out_size, void* d_ws, size_t ws_size,
                              hipStream_t stream) {
    const float* x       = (const float*)d_in[0];
    const float* freq    = (const float*)d_in[1];
    const float* mask    = (const float*)d_in[2];
    const float* w_attn  = (const float*)d_in[3];
    const float* w_ffn   = (const float*)d_in[4];
    const float* W_dq    = (const float*)d_in[5];
    const float* q_c_nrm = (const float*)d_in[6];
    const float* W_uq    = (const float*)d_in[7];
    const float* W_dkv   = (const float*)d_in[8];
    const float* kv_nrm  = (const float*)d_in[9];
    const float* W_ukv   = (const float*)d_in[10];
    const float* W_o     = (const float*)d_in[11];
    const float* W_r     = (const float*)d_in[12];
    const float* Ws_gate = (const float*)d_in[13];
    const float* Ws_up   = (const float*)d_in[14];
    const float* Ws_down = (const float*)d_in[15];
    const float* We_gate = (const float*)d_in[16];
    const float* We_up   = (const float*)d_in[17];
    const float* We_down = (const float*)d_in[18];
    float* out = (float*)d_out;
    char* ws = (char*)d_ws;
    (void)in_sizes; (void)n_in; (void)out_size;

    // ---- workspace layout (~283 MB + arena; known budget >= 357 MB) ----
    size_t o = 0;
    auto alloc = [&](size_t n) { size_t r = o; o += alignup(n); return r; };
    size_t oWslot = alloc((size_t)3072 * 3 * QCD * 2);       // 28.3 MB rotating slot
    size_t oQ3    = alloc((size_t)32 * SEQ * 3 * QDIM * 2);
    size_t oK3    = alloc((size_t)32 * SEQ * 3 * QDIM * 2);
    size_t oV3T   = alloc((size_t)32 * VHD * 3 * SEQ * 2);
    size_t oAttn3 = alloc((size_t)TOK * 3 * HIDD * 2);
    size_t oX2    = alloc((size_t)TOK * HIDD * 4);
    size_t oTbuf  = alloc((size_t)TOK * HIDD * 2);
    size_t oWts   = alloc((size_t)TOK * 8 * 4);
    size_t oPerm  = alloc((size_t)8 * TOK * 4);
    size_t oCnt   = alloc((size_t)8 * 4);
    size_t oKrope = alloc((size_t)TOK * ROPED * 4);
    // overlay arena: early chain | scores+P3 (16-head chunk) | hid8+WeguAll/WedAll (MoE)
    size_t zH3   = alignup((size_t)TOK * 3 * HIDD * 2);
    size_t zCqp  = alignup((size_t)TOK * QCD * 4);
    size_t zCq3  = alignup((size_t)TOK * 3 * QCD * 2);
    size_t zQp   = alignup((size_t)TOK * 3072 * 4);
    size_t zCkv  = alignup((size_t)TOK * KVDP * 4);
    size_t zKvc3 = alignup((size_t)TOK * 3 * KVCD * 2);
    size_t zKv   = alignup((size_t)TOK * 4096 * 4);
    size_t chain = zH3 + zCqp + zCq3 + zQp + zCkv + zKvc3 + zKv;
    size_t zScores = alignup((size_t)16 * SEQ * SEQ * 4);       // 67.1 MB
    size_t zP3     = alignup((size_t)16 * SEQ * 3 * SEQ * 2);   // 100.7 MB
    size_t zHid8   = alignup((size_t)8 * TOK * INTERD * 2);     // 46.2 MB
    size_t zWegu   = alignup((size_t)8 * GUD * HIDD * 2);       // 92.3 MB (WedAll overlays)
    size_t arenaSz = chain;
    if (zScores + zP3 > arenaSz) arenaSz = zScores + zP3;
    if (zHid8 + zWegu > arenaSz) arenaSz = zHid8 + zWegu;
    size_t oArena = alloc(arenaSz);
    if (ws_size < o) return;

    size_t oH3   = oArena;
    size_t oCqp  = oH3 + zH3;
    size_t oCq3  = oCqp + zCqp;
    size_t oQp   = oCq3 + zCq3;
    size_t oCkv  = oQp + zQp;
    size_t oKvc3 = oCkv + zCkv;
    size_t oKv   = oKvc3 + zKvc3;
    size_t oScores = oArena;
    size_t oP3     = oArena + zScores;
    size_t oHid8   = oArena;
    size_t oWegu   = oArena + zHid8;   // WedAll reuses this region after GU GEMM

    f16*  wslotH = (f16*)(ws + oWslot);                            // attn f16 triple
    bf16* wslotB = (bf16*)(ws + oWslot);                           // shared GU bf16 (interleaved)
    bf16* wslotB2 = (bf16*)(ws + oWslot + (size_t)GUD * HIDD * 2); // shared down bf16
    f16*  q3    = (f16*)(ws + oQ3);
    f16*  k3    = (f16*)(ws + oK3);
    f16*  v3T   = (f16*)(ws + oV3T);
    f16*  attn3 = (f16*)(ws + oAttn3);
    float* x2   = (float*)(ws + oX2);
    bf16* tbuf  = (bf16*)(ws + oTbuf);
    float* wts  = (float*)(ws + oWts);
    int*  perm  = (int*)(ws + oPerm);
    int*  counts = (int*)(ws + oCnt);
    float* krope = (float*)(ws + oKrope);
    f16*  h3    = (f16*)(ws + oH3);
    float* cqpre = (float*)(ws + oCqp);
    f16*  cq3   = (f16*)(ws + oCq3);
    float* qpre = (float*)(ws + oQp);
    float* ckv  = (float*)(ws + oCkv);
    f16*  kvc3  = (f16*)(ws + oKvc3);
    float* kv   = (float*)(ws + oKv);
    float* scores = (float*)(ws + oScores);
    f16*  P3    = (f16*)(ws + oP3);
    bf16* hid8  = (bf16*)(ws + oHid8);
    bf16* WeguAll = (bf16*)(ws + oWegu);
    bf16* WedAll  = (bf16*)(ws + oWegu);

    auto tconv3h = [&](const float* src, f16* dst, int K, int N, int Npad) {
        dim3 g((Npad + 31) / 32, (K + 31) / 32);
        tconv3h_kernel<<<g, 256, 0, stream>>>(src, dst, K, N, Npad);
    };
    auto tconvEx = [&](const float* gate, const float* up, const float* down) {
        tconv_ex3_kernel<<<dim3(64, 64, 3), 256, 0, stream>>>(gate, up, down, wslotB, wslotB2);
    };
    // fp16 GEMM launchers by tile shape
    auto gH128x128 = [&](const f16* A, const f16* B, void* C, const float* aux,
                         int M, int N, int K, int lda, int ldb, int ldc,
                         long sA, long sB, long sC, int Z, int mode, int auxLd, float osc) {
        dim3 g(N / 128, M / 128, Z);
        gemm_bt_kernel<1, 128, 128><<<g, 256, 0, stream>>>((const u16*)A, (const u16*)B, C, aux,
            nullptr, nullptr, K, lda, ldb, ldc, sA, sB, sC, mode, auxLd, osc);
    };
    auto gH128x64 = [&](const f16* A, const f16* B, void* C, const float* aux,
                        int M, int N, int K, int lda, int ldb, int ldc,
                        long sA, long sB, long sC, int Z, int mode, int auxLd, float osc) {
        dim3 g(N / 64, M / 128, Z);
        gemm_bt_kernel<1, 128, 64><<<g, 256, 0, stream>>>((const u16*)A, (const u16*)B, C, aux,
            nullptr, nullptr, K, lda, ldb, ldc, sA, sB, sC, mode, auxLd, osc);
    };
    auto gH64x64 = [&](const f16* A, const f16* B, void* C, const float* aux,
                       int M, int N, int K, int lda, int ldb, int ldc,
                       long sA, long sB, long sC, int Z, int mode, int auxLd, float osc) {
        dim3 g(N / 64, M / 64, Z);
        gemm_bt_kernel<1, 64, 64><<<g, 256, 0, stream>>>((const u16*)A, (const u16*)B, C, aux,
            nullptr, nullptr, K, lda, ldb, ldc, sA, sB, sC, mode, auxLd, osc);
    };
    auto gB128x64 = [&](const bf16* A, const bf16* B, void* C,
                        const float* aux, const int* idx, const int* cnt,
                        int M, int N, int K, int lda, int ldb, int ldc, int mode, int auxLd) {
        dim3 g(N / 64, M / 128, 1);
        gemm_bt_kernel<0, 128, 64><<<g, 256, 0, stream>>>((const u16*)A, (const u16*)B, C, aux,
            idx, cnt, K, lda, ldb, ldc, 0, 0, 0, mode, auxLd, 1.0f);
    };

    // ---- attention pipeline (split-fp16 3K-concat GEMMs) ----
    rmsnorm3h_kernel<<<TOK, 256, 0, stream>>>(x, w_attn, h3, HIDD);

    tconv3h(W_dq, wslotH, HIDD, QCD, QCD);
    gH128x64(h3, wslotH, cqpre, nullptr, TOK, QCD, 3 * HIDD, 3 * HIDD, 3 * HIDD, QCD,
             0, 0, 0, 1, 0, 0, OSC);
    rmsnorm3h_kernel<<<TOK, 256, 0, stream>>>(cqpre, q_c_nrm, cq3, QCD);

    tconv3h(W_uq, wslotH, QCD, 3072, 3072);
    gH128x128(cq3, wslotH, qpre, nullptr, TOK, 3072, 3 * QCD, 3 * QCD, 3 * QCD, 3072,
              0, 0, 0, 1, 0, 0, OSC);

    tconv3h(W_dkv, wslotH, HIDD, KVD, KVDP);
    gH64x64(h3, wslotH, ckv, nullptr, TOK, KVDP, 3 * HIDD, 3 * HIDD, 3 * HIDD, KVDP,
            0, 0, 0, 1, 0, 0, OSC);
    kvsplit3h_kernel<<<TOK, 256, 0, stream>>>(ckv, kv_nrm, freq, kvc3, krope);

    tconv3h(W_ukv, wslotH, KVCD, 4096, 4096);
    gH128x128(kvc3, wslotH, kv, nullptr, TOK, 4096, 3 * KVCD, 3 * KVCD, 3 * KVCD, 4096,
              0, 0, 0, 1, 0, 0, OSC);

    build_q3h_kernel<<<TOK, 256, 0, stream>>>(qpre, freq, q3);
    build_k3h_kernel<<<TOK, 256, 0, stream>>>(kv, krope, k3, v3T);

    for (int b = 0; b < 2; b++) {
        int h0 = b * NHEADS;
        gH128x128(q3 + (size_t)h0 * SEQ * 3 * QDIM, k3 + (size_t)h0 * SEQ * 3 * QDIM,
                  scores, nullptr, SEQ, SEQ, 3 * QDIM, 3 * QDIM, 3 * QDIM, SEQ,
                  (long)SEQ * 3 * QDIM, (long)SEQ * 3 * QDIM, (long)SEQ * SEQ, 16, 0, 0, OSC);
        softmax3h_kernel<<<dim3(SEQ, 16), 256, 0, stream>>>(scores, mask, P3,
                                                            1.f / sqrtf((float)QDIM));
        // PV: acc = 4096*P*V; store triple of 64*(P*V) -> osc = 1/64
        gH64x64(P3, v3T + (size_t)h0 * VHD * 3 * SEQ,
                attn3 + (size_t)b * SEQ * 3 * HIDD, nullptr,
                SEQ, VHD, 3 * SEQ, 3 * SEQ, 3 * SEQ, 3 * HIDD,
                (long)SEQ * 3 * SEQ, (long)VHD * 3 * SEQ, (long)VHD, 16, 6, HIDD,
                1.0f / SPS);
    }

    tconv3h(W_o, wslotH, HIDD, HIDD, HIDD);
    gH128x64(attn3, wslotH, x2, x, TOK, HIDD, 3 * HIDD, 3 * HIDD, 3 * HIDD, HIDD,
             0, 0, 0, 1, 2, HIDD, OSC);

    // ---- MoE ----
    rmsnorm_kernel<<<TOK, 256, 0, stream>>>(x2, w_ffn, tbuf, out, HIDD);  // out = x2
    zero_counts_kernel<<<1, 64, 0, stream>>>(counts);
    router_kernel<<<TOK, 64, 0, stream>>>(x2, w_ffn, W_r, wts, perm, counts);

    // shared experts (dense, rotating slot): fused silu GU -> hid8[0], down accumulate
    for (int e = 0; e < 2; e++) {
        tconvEx(Ws_gate + (size_t)e * HIDD * INTERD,
                Ws_up   + (size_t)e * HIDD * INTERD,
                Ws_down + (size_t)e * INTERD * HIDD);
        gB128x64(tbuf, wslotB, hid8, nullptr, nullptr, nullptr,
                 TOK, GUD, HIDD, HIDD, HIDD, GUD, 7, INTERD);
        gB128x64(hid8, wslotB2, out, nullptr, nullptr, nullptr,
                 TOK, HIDD, INTERD, INTERD, INTERD, HIDD, 3, 0);
    }

    // routed experts: grouped (4 launches total)
    // 1. all GU weights (interleaved) -> WeguAll
    tconv_guall_kernel<<<dim3(INTERD / 32, HIDD / 32, 16), 256, 0, stream>>>(
        We_gate, We_up, WeguAll);
    // 2. grouped fused-silu GU GEMM: A = tbuf via perm indirection, z = expert
    {
        dim3 g(GUD / 64, TOK / 64, 8);
        gemm_bt_kernel<0, 64, 64><<<g, 256, 0, stream>>>(
            (const u16*)tbuf, (const u16*)WeguAll, hid8, nullptr, perm, counts,
            HIDD, HIDD, HIDD, 0, 0, (long)GUD * HIDD, (long)TOK * INTERD, 7, INTERD, 1.0f);
    }
    // 3. all down weights -> WedAll (overlays WeguAll; GU GEMM already consumed it)
    tconv_downall_kernel<<<dim3(HIDD / 32, INTERD / 32, 8), 256, 0, stream>>>(
        We_down, WedAll);
    // 4. grouped down GEMM with atomic scatter: out[perm[z][row]] += wts[tok][z]*val
    {
        dim3 g(HIDD / 64, TOK / 64, 8);
        gemm_bt_kernel<0, 64, 64><<<g, 256, 0, stream>>>(
            (const u16*)hid8, (const u16*)WedAll, out, wts, perm, counts,
            INTERD, INTERD, INTERD, HIDD, (long)TOK * INTERD, (long)HIDD * INTERD, 0,
            5, 8, 1.0f);
    }
}